// Round 11
// baseline (325.559 us; speedup 1.0000x reference)
//
#include <hip/hip_runtime.h>
#include <math.h>

// RecursiveAttentiveEncoder — MoE-sorted MFMA, ws_size-adaptive chunking.
// R6 sort, R7 frag-pack+LDS-stage, R9 A-prefetch, R10 LDS-tiled transpose,
// R12 full-row writes + parallel attn, R13 2-deep A-prefetch + MR=96,
// R14 B-frag dbuf + setprio + merged barrier (300.3us, lvl0 70.1, 5.0M cf).
// R15 FAILED (311us): additive rotation cs+=4*(lm&7) contributes only
// 4*(lm&1) to the bank group (cs mod 8) -> h/y writes collapsed onto 4 of 8
// groups, conflicts 5.0M -> 16.45M. LESSON: bank group of a 16B chunk is
// cs mod 8; the XOR swizzle ^((lm&7)<<1) keeps lm bits 0-2 in the bank index
// and is at the floor on every access site. REVERTED to XOR everywhere.
// R16: (a) revert swizzle (keep MR64 lvl2/3 from R15 — banking-independent);
// (b) T14 async-STAGE split: x staged in two K-halves (c32<16 / >=16 —
// disjoint LDS slots under XOR since bit4 is preserved). half2's global
// loads issue before barrier1 and land after k0-3 (half2 write + barrier at
// k==4) -> random-gather HBM latency hides under k0-3 MFMA. Same arithmetic
// -> bit-identical.

typedef unsigned short u16;
typedef unsigned int   u32;
typedef unsigned long long u64;
typedef __attribute__((ext_vector_type(8))) short v8s;   // 8 bf16 (4 VGPRs)
typedef __attribute__((ext_vector_type(4))) float f32x4; // MFMA acc

__device__ __forceinline__ float b2f(u16 u) { return __uint_as_float(((u32)u) << 16); }
__device__ __forceinline__ u16 f2b(float f) {
  f = (f == f) ? f : 0.f;                    // NaN squash (hygiene)
  u32 x = __float_as_uint(f);
  u32 r = x + 0x7fffu + ((x >> 16) & 1u);
  return (u16)(r >> 16);
}

#define NTREE 34816   // B*T_TREES = 1024*34
#define RLEAF 9216    // B*(GT_MAX+1)

// ==================== per-chunk expert sort (node levels) ====================
// 3-pass counting sort. gid in [0,15*CB): [0,8CB)=lvl0, [8CB,12CB)=lvl1,
// [12CB,14CB)=lvl2, [14CB,15CB)=lvl3. CB multiple of 32 -> every level
// boundary is 64-aligned -> each wave is level-uniform (tail lanes id=-1).

// ---- pass A: per-block histogram (LDS atomics only; plain global stores) ----
__global__ __launch_bounds__(256) void perm_hist_k(
    const int* __restrict__ nf, int* __restrict__ bh,
    const int CB, const int bt0, const int nb)
{
  const int gid = blockIdx.x * 256 + threadIdx.x;
  int id = -1, lr = 0, cofs = 12, ioff = 14, shift = 0;
  if (gid < 8 * CB)       { lr = gid;          cofs = 0;  ioff = 0;  shift = 3; }
  else if (gid < 12 * CB) { lr = gid - 8*CB;   cofs = 4;  ioff = 8;  shift = 2; }
  else if (gid < 14 * CB) { lr = gid - 12*CB;  cofs = 8;  ioff = 12; shift = 1; }
  else if (gid < 15 * CB) { lr = gid - 14*CB;  /* lvl3 defaults above */        }
  if (gid < 15 * CB) {
    int bt = bt0 + (lr >> shift);
    int n  = lr & ((1 << shift) - 1);
    id = nf[bt * 15 + ioff + n];
  }
  __shared__ int lcnt[16];
  if (threadIdx.x < 16) lcnt[threadIdx.x] = 0;
  __syncthreads();
  const int lane = threadIdx.x & 63;
  #pragma unroll
  for (int e = 0; e < 4; ++e) {
    u64 m = __ballot(id == e);
    if (m && lane == __builtin_ctzll(m))
      atomicAdd(&lcnt[cofs + e], (int)__popcll(m));
  }
  __syncthreads();
  if (threadIdx.x < 16)
    bh[threadIdx.x * nb + blockIdx.x] = lcnt[threadIdx.x];
}

// ---- pass B: exclusive scan per slot (one wave per slot), totals -> cnt ----
__global__ __launch_bounds__(1024) void perm_scan_k(
    int* __restrict__ bh, int* __restrict__ cnt, const int nb)
{
  const int s = threadIdx.x >> 6;      // slot 0..15
  const int lane = threadIdx.x & 63;
  int carry = 0;
  for (int b0 = 0; b0 < nb; b0 += 64) {
    const int b = b0 + lane;
    int v = (b < nb) ? bh[s * nb + b] : 0;
    int x = v;                          // inclusive wave scan
    #pragma unroll
    for (int d = 1; d < 64; d <<= 1) {
      int y = __shfl_up(x, d);
      if (lane >= d) x += y;
    }
    if (b < nb) bh[s * nb + b] = carry + x - v;   // exclusive, in place
    carry += __shfl(x, 63);
  }
  if (lane == 0) cnt[s] = carry;       // bin totals (no atomics, no memset dep)
}

// ---- pass C: rank + scatter (no global atomics) ----
__global__ __launch_bounds__(256) void perm_scatter_k(
    const int* __restrict__ nf, const int* __restrict__ bh,
    int* __restrict__ perm, const int CB, const int bt0, const int nb)
{
  const int gid = blockIdx.x * 256 + threadIdx.x;
  int id = -1, lr = 0, rows = CB, cofs = 12, pofs = 56 * CB, ioff = 14, shift = 0;
  if (gid < 8 * CB)       { lr = gid;          rows = 8*CB; cofs = 0;  pofs = 0;      ioff = 0;  shift = 3; }
  else if (gid < 12 * CB) { lr = gid - 8*CB;   rows = 4*CB; cofs = 4;  pofs = 32*CB;  ioff = 8;  shift = 2; }
  else if (gid < 14 * CB) { lr = gid - 12*CB;  rows = 2*CB; cofs = 8;  pofs = 48*CB;  ioff = 12; shift = 1; }
  else if (gid < 15 * CB) { lr = gid - 14*CB;  /* lvl3 defaults above */               }
  if (gid < 15 * CB) {
    int bt = bt0 + (lr >> shift);
    int n  = lr & ((1 << shift) - 1);
    id = nf[bt * 15 + ioff + n];
  }
  __shared__ int wc[4][16];
  const int w = threadIdx.x >> 6, lane = threadIdx.x & 63;
  if (lane < 16) wc[w][lane] = 0;
  __syncthreads();
  u64 msave[4];
  #pragma unroll
  for (int e = 0; e < 4; ++e) {
    u64 m = __ballot(id == e);
    msave[e] = m;
    if (m && lane == __builtin_ctzll(m))
      wc[w][cofs + e] = (int)__popcll(m);
  }
  __syncthreads();
  #pragma unroll
  for (int e = 0; e < 4; ++e) {
    if (id == e) {
      const int slot = cofs + e;
      int base = bh[slot * nb + blockIdx.x];        // global rank of block's bin start
      #pragma unroll
      for (int w2 = 0; w2 < 3; ++w2)
        if (w2 < w) base += wc[w2][slot];           // intra-block wave prefix
      perm[pofs + e * rows + base +
           (int)__popcll(msave[e] & ((1ull << lane) - 1ull))] = lr;
    }
  }
}

// ==================== leaf-stage expert sort ====================
// 36 blocks x 3 experts -> ~144 atomics/address: negligible, keep single-pass.
__global__ __launch_bounds__(256) void leaf_perm_k(
    const int* __restrict__ lf, int* __restrict__ cnt, int* __restrict__ perm)
{
  const int gid = blockIdx.x * 256 + threadIdx.x;   // 36*256 = 9216 exact
  const int id = lf[gid];
  const int lane = threadIdx.x & 63;
  for (int e = 0; e < 3; ++e) {
    u64 m = __ballot(id == e);
    if (!m) continue;
    int leader = __builtin_ctzll(m);
    int bp = 0;
    if (lane == leader) bp = atomicAdd(&cnt[e], (int)__popcll(m));
    bp = __shfl(bp, leader);
    if (id == e)
      perm[e * RLEAF + bp + (int)__popcll(m & ((1ull << lane) - 1ull))] = gid;
  }
}

// ==================== weight convert + FRAGMENT-PACK (f32 -> bf16) ====================
// MFMA A-fragment for 16x16x32: lane l holds row=mt*16+(l&15), k=kt*32+(l>>4)*8+j.
// Packed block = 512 u16 = 1KB; wave load = base + lane*16B (coalesced).
// LDS-tiled: one 256-thread block = one 16x16 f32 source tile; coalesced 64B
// row reads; frag-packed write from LDS. (R10)
__global__ __launch_bounds__(256) void transpose_k(
    const float* __restrict__ s0, const float* __restrict__ s1,
    const float* __restrict__ s2, const float* __restrict__ s3,
    const float* __restrict__ s4,
    u16* __restrict__ d0, u16* __restrict__ d1, u16* __restrict__ d2,
    u16* __restrict__ d3, u16* __restrict__ d4)
{
  __shared__ float tile[16][17];
  const int t = threadIdx.x;
  const int idx0 = blockIdx.x * 256;           // block-uniform
  if (idx0 < 983040) {                         // the four frag-packed tensors
    const float* s; u16* d; int tb, estr, O, kt, mt, e;
    int tloc0;
    if (idx0 < 262144)      { s = s0; d = d0; tb = 0;      estr = 65536;  O = 256; }
    else if (idx0 < 393216) { s = s1; d = d1; tb = 262144; estr = 32768;  O = 128; }
    else if (idx0 < 786432) { s = s2; d = d2; tb = 393216; estr = 131072; O = 512; }
    else                    { s = s3; d = d3; tb = 786432; estr = 65536;  O = 128; }
    tloc0 = idx0 - tb;
    const int blk = tloc0 >> 9;                // frag-block id
    const int hb  = (tloc0 >> 8) & 1;          // which half of the frag block
    if (idx0 < 262144)      { kt = blk & 7;  mt = (blk >> 3) & 15; e = blk >> 7; }
    else if (idx0 < 393216) { kt = blk & 7;  mt = (blk >> 3) & 7;  e = blk >> 6; }
    else if (idx0 < 786432) { kt = blk & 7;  mt = (blk >> 3) & 31; e = blk >> 8; }
    else                    { kt = blk & 15; mt = (blk >> 4) & 7;  e = blk >> 7; }
    const int o0 = mt * 16;
    const int k0 = kt * 32 + hb * 16;
    // coalesced tile load: row k0+(t>>4), col o0+(t&15)
    tile[t >> 4][t & 15] = s[(size_t)e * estr + (size_t)(k0 + (t >> 4)) * O + o0 + (t & 15)];
    __syncthreads();
    d[tloc0 + t] = f2b(tile[((t >> 7) << 3) + (t & 7)][(t >> 3) & 15]);
  } else {                                     // ent_emb: already coalesced copy
    int tl = idx0 + t - 983040;
    d4[tl] = f2b(s4[tl]);
  }
}

// ==================== fused expert MLP ====================
// out[r] = relu(x[r] @ W1[bin] + b1[bin]) @ W2[bin] + b2[bin]
// h^T = W1f(A)*x^T(B); y^T = W2f(A)*h^T(B).   rc is a CHUNK-LOCAL row id.
// MODE 0: x = concat(embB[leaf_idx[bt*16+2n]], [..+2n+1]), bt = bt0+(rc>>3)
// MODE 1: x = src + rc*256 elems (pair of prev-level rows, contiguous 512B)
// MODE 2: x = roots rows (b*34+16+2g, +1), b = rc/9, g = rc%9 (contiguous 512B)
// x staged in LDS in two K-halves (XOR-swizzled; halves occupy disjoint slot
// sets since XOR preserves bit4). half2 global loads issue before barrier1,
// LDS-write + barrier at k==4 (T14 async-STAGE split).
// A-frags prefetched PD deep (2 for MT1<=4, 1 for leaf); B-frags (ds_read)
// double-buffered one k-step ahead; setprio(1) around MFMA clusters.
template<int HID, int NEXP, int MODE, int MR>
__global__ __launch_bounds__(256, 2) void mlp_k(
    const u16* __restrict__ src, const int* __restrict__ lidx,
    const u16* __restrict__ emb,
    const int* __restrict__ perm, const int* __restrict__ cnt,
    const int rows, const int bt0,
    const u16* __restrict__ W1f, const float* __restrict__ b1,
    const u16* __restrict__ W2f, const float* __restrict__ b2,
    u16* __restrict__ dst)
{
  constexpr int NT  = MR / 16;        // row tiles (B-operand)
  constexpr int MT1 = HID / 64;       // phase-1 m-tiles per wave
  constexpr int K2  = HID / 32;       // phase-2 k-tiles
  constexpr int PD1 = (MT1 <= 4) ? 2 : 1;   // phase-1 A-prefetch depth
  constexpr int NB1 = PD1 + 1;
  constexpr int NH  = MR / 16;        // uint4 loads per half per thread
  constexpr int XB  = MR * 512;       // x staging bytes (MR rows x 512B)
  constexpr int HB  = MR * HID * 2;   // hidden bytes
  constexpr int UB  = XB > HB ? XB : HB;
  __shared__ __align__(16) char uni[UB];       // x (ph1) -> h (ph2) -> y (epi)
  __shared__ int rid[MR], soff[2 * MR];
  u16* const xs = (u16*)uni;
  u16* const hs = (u16*)uni;

  int bin = -1, tile = 0, cb = 0;
  {
    int rem = blockIdx.x;
    #pragma unroll
    for (int e = 0; e < NEXP; ++e) {
      int ce = cnt[e];
      int tt = (ce + MR - 1) / MR;
      if (bin < 0) {
        if (rem < tt) { bin = e; tile = rem; cb = ce; }
        else rem -= tt;
      }
    }
  }
  if (bin < 0) return;
  const int rbase = tile * MR;
  const int tid = threadIdx.x;
  const int w  = tid >> 6;
  const int lane = tid & 63;
  const int lm = lane & 15;
  const int lq = lane >> 4;

  // A-frag base pointers: frag (m,k) at W1b + (m*8+k)*512 / W2b + (m*K2+k)*512
  const u16* const W1b = W1f + ((size_t)(bin * (HID / 16) + w * MT1) << 12) + lane * 8;
  const u16* const W2b = W2f + ((size_t)((bin * 8 + w * 2) * K2) << 9) + lane * 8;

  // ---- issue phase-1 A-frags k=0..PD1-1: latency hides under staging ----
  v8s afb[NB1][MT1];
  #pragma unroll
  for (int d = 0; d < PD1; ++d)
    #pragma unroll
    for (int m = 0; m < MT1; ++m)
      afb[d][m] = *(const v8s*)(W1b + (size_t)(m * 8 + d) * 512);

  // ---- row table + source offsets (merged, ONE sync) ----
  if (tid < MR) {
    int rl = rbase + tid;
    int rlc = rl < cb ? rl : (cb - 1);
    rlc = rlc < 0 ? 0 : rlc;
    int rc = perm[(size_t)bin * rows + rlc];
    rc = rc < 0 ? 0 : (rc >= rows ? rows - 1 : rc);   // defensive
    rid[tid] = (rl < cb) ? rc : -1;
    if (MODE == 0) {
      int bt = bt0 + (rc >> 3), node = rc & 7;
      int ia = lidx[bt * 16 + node * 2];
      int ib = lidx[bt * 16 + node * 2 + 1];
      ia = ia < 0 ? 0 : (ia > 1999 ? 1999 : ia);      // V_ENT=2000, defensive
      ib = ib < 0 ? 0 : (ib > 1999 ? 1999 : ib);
      soff[2 * tid]     = ia * 256;
      soff[2 * tid + 1] = ib * 256;
    } else {
      int base;
      if (MODE == 1) base = rc * 512;
      else { int bq = rc / 9, g = rc - bq * 9; base = (bq * 34 + 16 + 2 * g) * 256; }
      soff[2 * tid]     = base;
      soff[2 * tid + 1] = base + 256;
    }
  }
  __syncthreads();

  // ---- stage x half1 (K cols 0..127, chunks c32<16), issue half2 loads ----
  // half h chunk q: row r=q>>4, sub=q&15, c32=sub+16h, LDS slot cs=c32^((r&7)<<1).
  // XOR preserves bit4 -> half slot sets are disjoint. 16 consecutive lanes
  // read one 256B source segment contiguously (coalesced).
  const char* const sb = (MODE == 0) ? (const char*)emb : (const char*)src;
  uint4 x1[NH], x2[NH];
  #pragma unroll
  for (int i = 0; i < NH; ++i) {
    int q = i * 256 + tid, r = q >> 4, sub = q & 15;
    x1[i] = *(const uint4*)(sb + (size_t)(u32)soff[2 * r] + sub * 16);
  }
  #pragma unroll
  for (int i = 0; i < NH; ++i) {
    int q = i * 256 + tid, r = q >> 4, sub = q & 15;
    int cs = sub ^ ((r & 7) << 1);
    *(uint4*)(uni + r * 512 + cs * 16) = x1[i];
  }
  #pragma unroll
  for (int i = 0; i < NH; ++i) {               // half2: issue now, land at k==4
    int q = i * 256 + tid, r = q >> 4, sub = q & 15;
    x2[i] = *(const uint4*)(sb + (size_t)(u32)soff[2 * r + 1] + sub * 16);
  }
  __syncthreads();                             // half1 visible

  int rdn[NT];
  #pragma unroll
  for (int n = 0; n < NT; ++n) rdn[n] = rid[n * 16 + lm];

  // ---- phase 1: h^T = W1f * x^T, +b1, relu -> hs (same LDS) ----
  f32x4 acc[MT1][NT];
  #pragma unroll
  for (int m = 0; m < MT1; ++m)
    #pragma unroll
    for (int n = 0; n < NT; ++n)
      acc[m][n] = f32x4{0.f, 0.f, 0.f, 0.f};

  v8s bfr2[2][NT];
  #pragma unroll
  for (int n = 0; n < NT; ++n) {               // B k=0 (half1)
    int r = n * 16 + lm;
    int cs = lq ^ ((lm & 7) << 1);
    bfr2[0][n] = *(const v8s*)(xs + r * 256 + cs * 8);
  }
  #pragma unroll
  for (int k = 0; k < 8; ++k) {                // K = 256; halves split at k=4
    if (k == 4) {
      #pragma unroll
      for (int i = 0; i < NH; ++i) {           // write half2 (disjoint slots)
        int q = i * 256 + tid, r = q >> 4, sub = q & 15;
        int cs = (sub + 16) ^ ((r & 7) << 1);
        *(uint4*)(uni + r * 512 + cs * 16) = x2[i];
      }
      __syncthreads();
      #pragma unroll
      for (int n = 0; n < NT; ++n) {           // B k=4 direct (cb_=0)
        int r = n * 16 + lm;
        int cs = (16 + lq) ^ ((lm & 7) << 1);
        bfr2[0][n] = *(const v8s*)(xs + r * 256 + cs * 8);
      }
    }
    const int cur = k % NB1;
    if (k + PD1 < 8) {
      const int nx = (k + PD1) % NB1;
      #pragma unroll
      for (int m = 0; m < MT1; ++m)
        afb[nx][m] = *(const v8s*)(W1b + (size_t)(m * 8 + k + PD1) * 512);
    }
    const int cb_ = k & 1;
    if (k < 7 && k != 3) {                     // no prefetch across the k=4 barrier
      #pragma unroll
      for (int n = 0; n < NT; ++n) {           // B k+1 prefetch
        int r = n * 16 + lm;
        int cs = ((k + 1) * 4 + lq) ^ ((lm & 7) << 1);
        bfr2[cb_ ^ 1][n] = *(const v8s*)(xs + r * 256 + cs * 8);
      }
    }
    __builtin_amdgcn_s_setprio(1);
    #pragma unroll
    for (int m = 0; m < MT1; ++m)
      #pragma unroll
      for (int n = 0; n < NT; ++n)
        acc[m][n] = __builtin_amdgcn_mfma_f32_16x16x32_bf16(afb[cur][m], bfr2[cb_][n], acc[m][n], 0, 0, 0);
    __builtin_amdgcn_s_setprio(0);
  }

  // ---- issue phase-2 k=0,1 A-frags: latency hides under epilogue + barrier ----
  v8s afb2[3][2];
  #pragma unroll
  for (int m = 0; m < 2; ++m)
    afb2[0][m] = *(const v8s*)(W2b + (size_t)(m * K2) * 512);
  #pragma unroll
  for (int m = 0; m < 2; ++m)
    afb2[1][m] = *(const v8s*)(W2b + (size_t)(m * K2 + 1) * 512);

  __syncthreads();                           // all xs reads done before overwrite

  const float* b1b = b1 + bin * HID;
  #pragma unroll
  for (int m = 0; m < MT1; ++m) {
    const int f = (w * MT1 + m) * 16 + lq * 4;
    float bb0 = b1b[f], bb1 = b1b[f + 1], bb2 = b1b[f + 2], bb3 = b1b[f + 3];
    #pragma unroll
    for (int n = 0; n < NT; ++n) {
      union { u16 h[4]; uint2 v; } pk;
      f32x4 a = acc[m][n];
      pk.h[0] = f2b(fmaxf(a.x + bb0, 0.f));
      pk.h[1] = f2b(fmaxf(a.y + bb1, 0.f));
      pk.h[2] = f2b(fmaxf(a.z + bb2, 0.f));
      pk.h[3] = f2b(fmaxf(a.w + bb3, 0.f));
      int r = n * 16 + lm;
      int cs = (f >> 3) ^ ((lm & 7) << 1);
      *(uint2*)(uni + (size_t)r * (HID * 2) + (cs << 4) + (f & 7) * 2) = pk.v;
    }
  }
  __syncthreads();

  // ---- phase 2: y^T = W2f * h^T (2-deep A + 1-deep B prefetch) ----
  f32x4 acc2[2][NT];
  #pragma unroll
  for (int m = 0; m < 2; ++m)
    #pragma unroll
    for (int n = 0; n < NT; ++n)
      acc2[m][n] = f32x4{0.f, 0.f, 0.f, 0.f};

  #pragma unroll
  for (int n = 0; n < NT; ++n) {               // B k=0
    int r = n * 16 + lm;
    int cs = lq ^ ((lm & 7) << 1);
    bfr2[0][n] = *(const v8s*)(hs + (size_t)r * HID + cs * 8);
  }
  #pragma unroll
  for (int k = 0; k < K2; ++k) {
    const int cur = k % 3;
    if (k < K2 - 2) {
      const int nx2 = (k + 2) % 3;
      #pragma unroll
      for (int m = 0; m < 2; ++m)
        afb2[nx2][m] = *(const v8s*)(W2b + (size_t)(m * K2 + k + 2) * 512);
    }
    const int cb_ = k & 1;
    if (k < K2 - 1) {
      #pragma unroll
      for (int n = 0; n < NT; ++n) {           // B k+1 prefetch
        int r = n * 16 + lm;
        int cs = ((k + 1) * 4 + lq) ^ ((lm & 7) << 1);
        bfr2[cb_ ^ 1][n] = *(const v8s*)(hs + (size_t)r * HID + cs * 8);
      }
    }
    __builtin_amdgcn_s_setprio(1);
    #pragma unroll
    for (int m = 0; m < 2; ++m)
      #pragma unroll
      for (int n = 0; n < NT; ++n)
        acc2[m][n] = __builtin_amdgcn_mfma_f32_16x16x32_bf16(afb2[cur][m], bfr2[cb_][n], acc2[m][n], 0, 0, 0);
    __builtin_amdgcn_s_setprio(0);
  }

  // ---- epilogue: y -> LDS (XOR-swizzled), FULL-ROW coalesced global write ----
  __syncthreads();                           // all hs reads complete
  const float* b2b = b2 + bin * 128;
  #pragma unroll
  for (int m = 0; m < 2; ++m) {
    const int f = (w * 2 + m) * 16 + lq * 4;
    float bb0 = b2b[f], bb1 = b2b[f + 1], bb2 = b2b[f + 2], bb3 = b2b[f + 3];
    #pragma unroll
    for (int n = 0; n < NT; ++n) {
      union { u16 h[4]; uint2 v; } pk;
      f32x4 a = acc2[m][n];
      pk.h[0] = f2b(a.x + bb0);
      pk.h[1] = f2b(a.y + bb1);
      pk.h[2] = f2b(a.z + bb2);
      pk.h[3] = f2b(a.w + bb3);
      int r = n * 16 + lm;
      int c = (w * 2 + m) * 2 + (lq >> 1);      // 16B chunk within 256B row
      int cs = c ^ ((lm & 7) << 1);
      *(uint2*)(uni + r * 256 + cs * 16 + (lq & 1) * 8) = pk.v;
    }
  }
  __syncthreads();
  // 16 lanes per row: full 256B contiguous lines, no partial-sector RMW
  #pragma unroll
  for (int i = 0; i < MR / 16; ++i) {
    int cg = i * 256 + tid;
    int r = cg >> 4, sub = cg & 15;
    int rg = rid[r];
    if (rg >= 0) {
      uint4 v = *(const uint4*)(uni + r * 256 + ((sub ^ ((r & 7) << 1)) << 4));
      *(uint4*)((char*)dst + (size_t)rg * 256 + sub * 16) = v;
    }
  }
}

// ==================== attention + concat (fp32) ====================
// R12: scores 8-lanes-per-key with shfl_xor reduce; wave-parallel softmax.
__global__ __launch_bounds__(128) void attn_k(
    const u16* __restrict__ stmt, const u16* __restrict__ roots,
    const float* __restrict__ themb, const int* __restrict__ thidx,
    const float* __restrict__ wHe, const float* __restrict__ bHe,
    const float* __restrict__ wHg, const float* __restrict__ bHg,
    const float* __restrict__ wHt, const float* __restrict__ bHt,
    float* __restrict__ out)
{
  const int b = blockIdx.x, t = threadIdx.x;   // 128 threads
  __shared__ float obj_s[128], q_s[128], keys_s[16 * 132], a_s[16];

  const float obj = b2f(stmt[((size_t)b * 9 + 8) * 128 + t]);
  obj_s[t] = obj;
  out[(size_t)b * 512 + t] = obj;              // obj passthrough
  __syncthreads();

  for (int a = 0; a < 3; ++a) {               // 0: gt_ctx, 1: ent_ctx, 2: th_ctx
    int cntk;
    const float *Wt, *bv;
    if (a == 0) {
      cntk = 8; Wt = wHg; bv = bHg;
      for (int j = 0; j < 8; ++j)
        keys_s[j * 132 + t] = b2f(stmt[((size_t)b * 9 + j) * 128 + t]);
    } else if (a == 1) {
      cntk = 16; Wt = wHe; bv = bHe;
      for (int j = 0; j < 16; ++j)
        keys_s[j * 132 + t] = b2f(roots[((size_t)b * 34 + j) * 128 + t]);
    } else {
      cntk = 8; Wt = wHt; bv = bHt;           // TH_MAX = 8
      for (int j = 0; j < 8; ++j) {
        int ti = thidx[b * 8 + j] & 31;        // V_TH = 32
        keys_s[j * 132 + t] = themb[(size_t)ti * 128 + t];
      }
    }
    // q[t] = b[t] + sum_k obj[k] * W[k][t]  (raw [in][out] layout, lane-coalesced)
    float qa = bv[t];
    for (int k = 0; k < 128; ++k) qa += obj_s[k] * Wt[k * 128 + t];
    q_s[t] = (qa == qa) ? qa : 0.f;
    __syncthreads();
    // scores: key j = t>>3, 8 lanes each sum 16 dims, shfl_xor tree reduce
    {
      int j = t >> 3, s = t & 7;
      if (j < cntk) {
        float sc = 0.f;
        #pragma unroll
        for (int k = 0; k < 16; ++k)
          sc += keys_s[j * 132 + s * 16 + k] * q_s[s * 16 + k];
        sc += __shfl_xor(sc, 1);
        sc += __shfl_xor(sc, 2);
        sc += __shfl_xor(sc, 4);
        if (s == 0) a_s[j] = (sc == sc) ? sc : 0.f;
      }
    }
    __syncthreads();
    // wave-parallel softmax over <=16 keys (lanes 0..15 of wave 0)
    if (t < 16) {
      float v = (t < cntk) ? a_s[t] : -3.0e38f;
      float mx = v;
      #pragma unroll
      for (int d = 1; d < 16; d <<= 1) mx = fmaxf(mx, __shfl_xor(mx, d));
      float e = (t < cntk) ? expf(v - mx) : 0.f;
      float sm = e;
      #pragma unroll
      for (int d = 1; d < 16; d <<= 1) sm += __shfl_xor(sm, d);
      if (t < cntk) a_s[t] = e / sm;
    }
    __syncthreads();
    float c = 0.f;
    for (int j = 0; j < cntk; ++j) c += a_s[j] * keys_s[j * 132 + t];
    out[(size_t)b * 512 + 128 * (a + 1) + t] = c;
    __syncthreads();
  }
}

// ==================== launch ====================
extern "C" void kernel_launch(void* const* d_in, const int* in_sizes, int n_in,
                              void* d_out, int out_size, void* d_ws, size_t ws_size,
                              hipStream_t stream)
{
  const int*   leaf_idx = (const int*)d_in[0];
  const int*   nf_ids   = (const int*)d_in[1];
  const int*   lf_ids   = (const int*)d_in[2];
  const int*   th_idx   = (const int*)d_in[3];
  const float* ent_emb  = (const float*)d_in[4];
  const float* th_emb   = (const float*)d_in[5];
  const float* nf_W1 = (const float*)d_in[6];
  const float* nf_b1 = (const float*)d_in[7];
  const float* nf_W2 = (const float*)d_in[8];
  const float* nf_b2 = (const float*)d_in[9];
  const float* lf_W1 = (const float*)d_in[10];
  const float* lf_b1 = (const float*)d_in[11];
  const float* lf_W2 = (const float*)d_in[12];
  const float* lf_b2 = (const float*)d_in[13];
  const float* he_W = (const float*)d_in[14];
  const float* he_b = (const float*)d_in[15];
  const float* hg_W = (const float*)d_in[16];
  const float* hg_b = (const float*)d_in[17];
  const float* ht_W = (const float*)d_in[18];
  const float* ht_b = (const float*)d_in[19];

  // ---- choose chunk size CB (trees per chunk) from ws_size ----
  // footprint ~= 14.5 MB fixed + CB*3320 B (perm 240 + bufA 2048 + bufB 1024 + bh ~4)
  int CB = NTREE;                              // 34816 -> full, no chunking
  while (CB > 544 && 14500000ull + (unsigned long long)CB * 3320ull > (unsigned long long)ws_size)
    CB >>= 1;                                  // 34816,17408,8704,4352,2176,1088,544
  const int nch = NTREE / CB;
  const int NB = (15 * CB + 255) / 256;        // blocks per chunk for the sort passes

  char* ws = (char*)d_ws;
  size_t off = 0;
  auto take = [&](size_t bytes) -> char* {
    char* p = ws + off;
    off = (off + bytes + 255) & ~(size_t)255;
    return p;
  };
  int* cnt      = (int*)take(8192);                       // nch*16 node + 8 leaf
  int* leafperm = (int*)take((size_t)3 * RLEAF * 4);      // 110.6 KB
  int* chperm   = (int*)take((size_t)60 * CB * 4);        // 4 bins x 15CB rows
  int* bh       = (int*)take((size_t)16 * NB * 4);        // block histograms/offsets
  u16* wN1  = (u16*)take((size_t)4 * 256 * 256 * 2);      // 512 KB (frag-packed)
  u16* wN2  = (u16*)take((size_t)4 * 128 * 256 * 2);      // 256 KB
  u16* wL1  = (u16*)take((size_t)3 * 512 * 256 * 2);      // 786 KB
  u16* wL2  = (u16*)take((size_t)3 * 128 * 512 * 2);      // 393 KB
  u16* embB = (u16*)take((size_t)2000 * 128 * 2);         // 512 KB
  u16* bufA  = (u16*)take((size_t)CB * 8 * 128 * 2);      // lvl0 out / lvl2 out
  u16* bufB  = (u16*)take((size_t)CB * 4 * 128 * 2);      // lvl1 out
  u16* roots = (u16*)take((size_t)NTREE * 128 * 2);       // 8.91 MB
  u16* stmt  = (u16*)take((size_t)RLEAF * 128 * 2);       // 2.36 MB

  int* leafcnt = cnt + nch * 16;

  hipMemsetAsync(cnt, 0, (size_t)(nch * 16 + 8) * 4, stream);
  transpose_k<<<4840, 256, 0, stream>>>(nf_W1, nf_W2, lf_W1, lf_W2, ent_emb,
                                        wN1, wN2, wL1, wL2, embB);
  leaf_perm_k<<<36, 256, 0, stream>>>(lf_ids, leafcnt, leafperm);

  for (int c = 0; c < nch; ++c) {
    const int bt0 = c * CB;
    int* ccnt = cnt + c * 16;
    perm_hist_k<<<NB, 256, 0, stream>>>(nf_ids, bh, CB, bt0, NB);
    perm_scan_k<<<1, 1024, 0, stream>>>(bh, ccnt, NB);
    perm_scatter_k<<<NB, 256, 0, stream>>>(nf_ids, bh, chperm, CB, bt0, NB);
    mlp_k<256, 4, 0, 96><<<(8 * CB + 95) / 96 + 4, 256, 0, stream>>>(
        nullptr, leaf_idx, embB, chperm, ccnt, 8 * CB, bt0,
        wN1, nf_b1, wN2, nf_b2, bufA);
    mlp_k<256, 4, 1, 96><<<(4 * CB + 95) / 96 + 4, 256, 0, stream>>>(
        bufA, nullptr, nullptr, chperm + 32 * CB, ccnt + 4, 4 * CB, 0,
        wN1, nf_b1, wN2, nf_b2, bufB);
    mlp_k<256, 4, 1, 64><<<(2 * CB + 63) / 64 + 4, 256, 0, stream>>>(
        bufB, nullptr, nullptr, chperm + 48 * CB, ccnt + 8, 2 * CB, 0,
        wN1, nf_b1, wN2, nf_b2, bufA);
    mlp_k<256, 4, 1, 64><<<(CB + 63) / 64 + 4, 256, 0, stream>>>(
        bufA, nullptr, nullptr, chperm + 56 * CB, ccnt + 12, CB, 0,
        wN1, nf_b1, wN2, nf_b2, roots + (size_t)bt0 * 128);
  }

  mlp_k<512, 3, 2, 32><<<RLEAF / 32 + 3, 256, 0, stream>>>(
      roots, nullptr, nullptr, leafperm, leafcnt, RLEAF, 0,
      wL1, lf_b1, wL2, lf_b2, stmt);

  attn_k<<<1024, 128, 0, stream>>>(stmt, roots, th_emb, th_idx,
                                   he_W, he_b, hg_W, hg_b, ht_W, ht_b,
                                   (float*)d_out);
}

// Round 12
// 298.428 us; speedup vs baseline: 1.0909x; 1.0909x over previous
//
#include <hip/hip_runtime.h>
#include <math.h>

// RecursiveAttentiveEncoder — MoE-sorted MFMA, ws_size-adaptive chunking.
// R6 sort, R7 frag-pack+LDS-stage, R9 A-prefetch, R10 LDS-tiled transpose,
// R12 full-row writes + parallel attn, R13 2-deep A-prefetch + MR=96,
// R14 B-frag dbuf + setprio + merged barrier (300.3us, lvl0 70.1, 5.0M cf).
// R15 FAILED (311us): additive-rotation swizzle dropped lm bits1-2 from the
// bank group (cs mod 8) -> 4-of-8-group collapse, conflicts 3.3x. XOR is
// at the floor; NEVER re-derive the bank map by intuition.
// R16 FAILED (325.6us): async-STAGE split held x1+x2 (48 VGPR) live at the
// issue point -> unified budget exceeded -> x2 spilled to scratch (WRITE
// 69.6->139MB, FETCH 9.9->26.6MB). Register-staged splits must budget both
// halves at peak. REVERTED.
// R17: R14 kernel verbatim + MR64 for lvl2/lvl3 only (tail quantization:
// 2CB/64 and CB/64 blocks at ~2/3 lifetime beat 1.42/0.71 rounds of MR96).

typedef unsigned short u16;
typedef unsigned int   u32;
typedef unsigned long long u64;
typedef __attribute__((ext_vector_type(8))) short v8s;   // 8 bf16 (4 VGPRs)
typedef __attribute__((ext_vector_type(4))) float f32x4; // MFMA acc

__device__ __forceinline__ float b2f(u16 u) { return __uint_as_float(((u32)u) << 16); }
__device__ __forceinline__ u16 f2b(float f) {
  f = (f == f) ? f : 0.f;                    // NaN squash (hygiene)
  u32 x = __float_as_uint(f);
  u32 r = x + 0x7fffu + ((x >> 16) & 1u);
  return (u16)(r >> 16);
}

#define NTREE 34816   // B*T_TREES = 1024*34
#define RLEAF 9216    // B*(GT_MAX+1)

// ==================== per-chunk expert sort (node levels) ====================
// 3-pass counting sort. gid in [0,15*CB): [0,8CB)=lvl0, [8CB,12CB)=lvl1,
// [12CB,14CB)=lvl2, [14CB,15CB)=lvl3. CB multiple of 32 -> every level
// boundary is 64-aligned -> each wave is level-uniform (tail lanes id=-1).

// ---- pass A: per-block histogram (LDS atomics only; plain global stores) ----
__global__ __launch_bounds__(256) void perm_hist_k(
    const int* __restrict__ nf, int* __restrict__ bh,
    const int CB, const int bt0, const int nb)
{
  const int gid = blockIdx.x * 256 + threadIdx.x;
  int id = -1, lr = 0, cofs = 12, ioff = 14, shift = 0;
  if (gid < 8 * CB)       { lr = gid;          cofs = 0;  ioff = 0;  shift = 3; }
  else if (gid < 12 * CB) { lr = gid - 8*CB;   cofs = 4;  ioff = 8;  shift = 2; }
  else if (gid < 14 * CB) { lr = gid - 12*CB;  cofs = 8;  ioff = 12; shift = 1; }
  else if (gid < 15 * CB) { lr = gid - 14*CB;  /* lvl3 defaults above */        }
  if (gid < 15 * CB) {
    int bt = bt0 + (lr >> shift);
    int n  = lr & ((1 << shift) - 1);
    id = nf[bt * 15 + ioff + n];
  }
  __shared__ int lcnt[16];
  if (threadIdx.x < 16) lcnt[threadIdx.x] = 0;
  __syncthreads();
  const int lane = threadIdx.x & 63;
  #pragma unroll
  for (int e = 0; e < 4; ++e) {
    u64 m = __ballot(id == e);
    if (m && lane == __builtin_ctzll(m))
      atomicAdd(&lcnt[cofs + e], (int)__popcll(m));
  }
  __syncthreads();
  if (threadIdx.x < 16)
    bh[threadIdx.x * nb + blockIdx.x] = lcnt[threadIdx.x];
}

// ---- pass B: exclusive scan per slot (one wave per slot), totals -> cnt ----
__global__ __launch_bounds__(1024) void perm_scan_k(
    int* __restrict__ bh, int* __restrict__ cnt, const int nb)
{
  const int s = threadIdx.x >> 6;      // slot 0..15
  const int lane = threadIdx.x & 63;
  int carry = 0;
  for (int b0 = 0; b0 < nb; b0 += 64) {
    const int b = b0 + lane;
    int v = (b < nb) ? bh[s * nb + b] : 0;
    int x = v;                          // inclusive wave scan
    #pragma unroll
    for (int d = 1; d < 64; d <<= 1) {
      int y = __shfl_up(x, d);
      if (lane >= d) x += y;
    }
    if (b < nb) bh[s * nb + b] = carry + x - v;   // exclusive, in place
    carry += __shfl(x, 63);
  }
  if (lane == 0) cnt[s] = carry;       // bin totals (no atomics, no memset dep)
}

// ---- pass C: rank + scatter (no global atomics) ----
__global__ __launch_bounds__(256) void perm_scatter_k(
    const int* __restrict__ nf, const int* __restrict__ bh,
    int* __restrict__ perm, const int CB, const int bt0, const int nb)
{
  const int gid = blockIdx.x * 256 + threadIdx.x;
  int id = -1, lr = 0, rows = CB, cofs = 12, pofs = 56 * CB, ioff = 14, shift = 0;
  if (gid < 8 * CB)       { lr = gid;          rows = 8*CB; cofs = 0;  pofs = 0;      ioff = 0;  shift = 3; }
  else if (gid < 12 * CB) { lr = gid - 8*CB;   rows = 4*CB; cofs = 4;  pofs = 32*CB;  ioff = 8;  shift = 2; }
  else if (gid < 14 * CB) { lr = gid - 12*CB;  rows = 2*CB; cofs = 8;  pofs = 48*CB;  ioff = 12; shift = 1; }
  else if (gid < 15 * CB) { lr = gid - 14*CB;  /* lvl3 defaults above */               }
  if (gid < 15 * CB) {
    int bt = bt0 + (lr >> shift);
    int n  = lr & ((1 << shift) - 1);
    id = nf[bt * 15 + ioff + n];
  }
  __shared__ int wc[4][16];
  const int w = threadIdx.x >> 6, lane = threadIdx.x & 63;
  if (lane < 16) wc[w][lane] = 0;
  __syncthreads();
  u64 msave[4];
  #pragma unroll
  for (int e = 0; e < 4; ++e) {
    u64 m = __ballot(id == e);
    msave[e] = m;
    if (m && lane == __builtin_ctzll(m))
      wc[w][cofs + e] = (int)__popcll(m);
  }
  __syncthreads();
  #pragma unroll
  for (int e = 0; e < 4; ++e) {
    if (id == e) {
      const int slot = cofs + e;
      int base = bh[slot * nb + blockIdx.x];        // global rank of block's bin start
      #pragma unroll
      for (int w2 = 0; w2 < 3; ++w2)
        if (w2 < w) base += wc[w2][slot];           // intra-block wave prefix
      perm[pofs + e * rows + base +
           (int)__popcll(msave[e] & ((1ull << lane) - 1ull))] = lr;
    }
  }
}

// ==================== leaf-stage expert sort ====================
// 36 blocks x 3 experts -> ~144 atomics/address: negligible, keep single-pass.
__global__ __launch_bounds__(256) void leaf_perm_k(
    const int* __restrict__ lf, int* __restrict__ cnt, int* __restrict__ perm)
{
  const int gid = blockIdx.x * 256 + threadIdx.x;   // 36*256 = 9216 exact
  const int id = lf[gid];
  const int lane = threadIdx.x & 63;
  for (int e = 0; e < 3; ++e) {
    u64 m = __ballot(id == e);
    if (!m) continue;
    int leader = __builtin_ctzll(m);
    int bp = 0;
    if (lane == leader) bp = atomicAdd(&cnt[e], (int)__popcll(m));
    bp = __shfl(bp, leader);
    if (id == e)
      perm[e * RLEAF + bp + (int)__popcll(m & ((1ull << lane) - 1ull))] = gid;
  }
}

// ==================== weight convert + FRAGMENT-PACK (f32 -> bf16) ====================
// MFMA A-fragment for 16x16x32: lane l holds row=mt*16+(l&15), k=kt*32+(l>>4)*8+j.
// Packed block = 512 u16 = 1KB; wave load = base + lane*16B (coalesced).
// LDS-tiled: one 256-thread block = one 16x16 f32 source tile; coalesced 64B
// row reads; frag-packed write from LDS. (R10)
__global__ __launch_bounds__(256) void transpose_k(
    const float* __restrict__ s0, const float* __restrict__ s1,
    const float* __restrict__ s2, const float* __restrict__ s3,
    const float* __restrict__ s4,
    u16* __restrict__ d0, u16* __restrict__ d1, u16* __restrict__ d2,
    u16* __restrict__ d3, u16* __restrict__ d4)
{
  __shared__ float tile[16][17];
  const int t = threadIdx.x;
  const int idx0 = blockIdx.x * 256;           // block-uniform
  if (idx0 < 983040) {                         // the four frag-packed tensors
    const float* s; u16* d; int tb, estr, O, kt, mt, e;
    int tloc0;
    if (idx0 < 262144)      { s = s0; d = d0; tb = 0;      estr = 65536;  O = 256; }
    else if (idx0 < 393216) { s = s1; d = d1; tb = 262144; estr = 32768;  O = 128; }
    else if (idx0 < 786432) { s = s2; d = d2; tb = 393216; estr = 131072; O = 512; }
    else                    { s = s3; d = d3; tb = 786432; estr = 65536;  O = 128; }
    tloc0 = idx0 - tb;
    const int blk = tloc0 >> 9;                // frag-block id
    const int hb  = (tloc0 >> 8) & 1;          // which half of the frag block
    if (idx0 < 262144)      { kt = blk & 7;  mt = (blk >> 3) & 15; e = blk >> 7; }
    else if (idx0 < 393216) { kt = blk & 7;  mt = (blk >> 3) & 7;  e = blk >> 6; }
    else if (idx0 < 786432) { kt = blk & 7;  mt = (blk >> 3) & 31; e = blk >> 8; }
    else                    { kt = blk & 15; mt = (blk >> 4) & 7;  e = blk >> 7; }
    const int o0 = mt * 16;
    const int k0 = kt * 32 + hb * 16;
    // coalesced tile load: row k0+(t>>4), col o0+(t&15)
    tile[t >> 4][t & 15] = s[(size_t)e * estr + (size_t)(k0 + (t >> 4)) * O + o0 + (t & 15)];
    __syncthreads();
    d[tloc0 + t] = f2b(tile[((t >> 7) << 3) + (t & 7)][(t >> 3) & 15]);
  } else {                                     // ent_emb: already coalesced copy
    int tl = idx0 + t - 983040;
    d4[tl] = f2b(s4[tl]);
  }
}

// ==================== fused expert MLP ====================
// out[r] = relu(x[r] @ W1[bin] + b1[bin]) @ W2[bin] + b2[bin]
// h^T = W1f(A)*x^T(B); y^T = W2f(A)*h^T(B).   rc is a CHUNK-LOCAL row id.
// MODE 0: x = concat(embB[leaf_idx[bt*16+2n]], [..+2n+1]), bt = bt0+(rc>>3)
// MODE 1: x = src + rc*256 elems (pair of prev-level rows, contiguous 512B)
// MODE 2: x = roots rows (b*34+16+2g, +1), b = rc/9, g = rc%9 (contiguous 512B)
// x staged in LDS (XOR-swizzled); hs and then y reuse the same LDS region.
// A-frags prefetched PD deep (2 for MT1<=4, 1 for leaf); B-frags (ds_read)
// double-buffered one k-step ahead; setprio(1) around MFMA clusters.
template<int HID, int NEXP, int MODE, int MR>
__global__ __launch_bounds__(256, 2) void mlp_k(
    const u16* __restrict__ src, const int* __restrict__ lidx,
    const u16* __restrict__ emb,
    const int* __restrict__ perm, const int* __restrict__ cnt,
    const int rows, const int bt0,
    const u16* __restrict__ W1f, const float* __restrict__ b1,
    const u16* __restrict__ W2f, const float* __restrict__ b2,
    u16* __restrict__ dst)
{
  constexpr int NT  = MR / 16;        // row tiles (B-operand)
  constexpr int MT1 = HID / 64;       // phase-1 m-tiles per wave
  constexpr int K2  = HID / 32;       // phase-2 k-tiles
  constexpr int PD1 = (MT1 <= 4) ? 2 : 1;   // phase-1 A-prefetch depth
  constexpr int NB1 = PD1 + 1;
  constexpr int XB  = MR * 512;       // x staging bytes (MR rows x 512B)
  constexpr int HB  = MR * HID * 2;   // hidden bytes
  constexpr int UB  = XB > HB ? XB : HB;
  __shared__ __align__(16) char uni[UB];       // x (ph1) -> h (ph2) -> y (epi)
  __shared__ int rid[MR], soff[2 * MR];
  u16* const xs = (u16*)uni;
  u16* const hs = (u16*)uni;

  int bin = -1, tile = 0, cb = 0;
  {
    int rem = blockIdx.x;
    #pragma unroll
    for (int e = 0; e < NEXP; ++e) {
      int ce = cnt[e];
      int tt = (ce + MR - 1) / MR;
      if (bin < 0) {
        if (rem < tt) { bin = e; tile = rem; cb = ce; }
        else rem -= tt;
      }
    }
  }
  if (bin < 0) return;
  const int rbase = tile * MR;
  const int tid = threadIdx.x;
  const int w  = tid >> 6;
  const int lane = tid & 63;
  const int lm = lane & 15;
  const int lq = lane >> 4;

  // A-frag base pointers: frag (m,k) at W1b + (m*8+k)*512 / W2b + (m*K2+k)*512
  const u16* const W1b = W1f + ((size_t)(bin * (HID / 16) + w * MT1) << 12) + lane * 8;
  const u16* const W2b = W2f + ((size_t)((bin * 8 + w * 2) * K2) << 9) + lane * 8;

  // ---- issue phase-1 A-frags k=0..PD1-1: latency hides under staging ----
  v8s afb[NB1][MT1];
  #pragma unroll
  for (int d = 0; d < PD1; ++d)
    #pragma unroll
    for (int m = 0; m < MT1; ++m)
      afb[d][m] = *(const v8s*)(W1b + (size_t)(m * 8 + d) * 512);

  // ---- row table + source offsets (merged, ONE sync) ----
  if (tid < MR) {
    int rl = rbase + tid;
    int rlc = rl < cb ? rl : (cb - 1);
    rlc = rlc < 0 ? 0 : rlc;
    int rc = perm[(size_t)bin * rows + rlc];
    rc = rc < 0 ? 0 : (rc >= rows ? rows - 1 : rc);   // defensive
    rid[tid] = (rl < cb) ? rc : -1;
    if (MODE == 0) {
      int bt = bt0 + (rc >> 3), node = rc & 7;
      int ia = lidx[bt * 16 + node * 2];
      int ib = lidx[bt * 16 + node * 2 + 1];
      ia = ia < 0 ? 0 : (ia > 1999 ? 1999 : ia);      // V_ENT=2000, defensive
      ib = ib < 0 ? 0 : (ib > 1999 ? 1999 : ib);
      soff[2 * tid]     = ia * 256;
      soff[2 * tid + 1] = ib * 256;
    } else {
      int base;
      if (MODE == 1) base = rc * 512;
      else { int bq = rc / 9, g = rc - bq * 9; base = (bq * 34 + 16 + 2 * g) * 256; }
      soff[2 * tid]     = base;
      soff[2 * tid + 1] = base + 256;
    }
  }
  __syncthreads();

  // ---- stage x into LDS, coalesced + XOR-swizzled ----
  // chunk c of MR*32: seg=c>>4 (256B), sub=c&15 (16B). 16 consecutive lanes
  // read one segment contiguously. LDS: row r (512B), chunk c32 stored at
  // c32 ^ ((r&7)<<1).
  const char* const sb = (MODE == 0) ? (const char*)emb : (const char*)src;
  #pragma unroll
  for (int i = 0; i < MR / 8; ++i) {
    int c = i * 256 + tid;
    int seg = c >> 4, sub = c & 15;
    uint4 v = *(const uint4*)(sb + (size_t)(u32)soff[seg] + sub * 16);
    int r = seg >> 1;
    int c32 = ((seg & 1) << 4) + sub;
    int cs = c32 ^ ((r & 7) << 1);
    *(uint4*)(uni + r * 512 + cs * 16) = v;
  }
  __syncthreads();

  int rdn[NT];
  #pragma unroll
  for (int n = 0; n < NT; ++n) rdn[n] = rid[n * 16 + lm];

  // ---- phase 1: h^T = W1f * x^T, +b1, relu -> hs (same LDS) ----
  f32x4 acc[MT1][NT];
  #pragma unroll
  for (int m = 0; m < MT1; ++m)
    #pragma unroll
    for (int n = 0; n < NT; ++n)
      acc[m][n] = f32x4{0.f, 0.f, 0.f, 0.f};

  v8s bfr2[2][NT];
  #pragma unroll
  for (int n = 0; n < NT; ++n) {               // B k=0
    int r = n * 16 + lm;
    int cs = lq ^ ((lm & 7) << 1);
    bfr2[0][n] = *(const v8s*)(xs + r * 256 + cs * 8);
  }
  #pragma unroll
  for (int k = 0; k < 8; ++k) {                // K = 256
    const int cur = k % NB1;
    if (k + PD1 < 8) {
      const int nx = (k + PD1) % NB1;
      #pragma unroll
      for (int m = 0; m < MT1; ++m)
        afb[nx][m] = *(const v8s*)(W1b + (size_t)(m * 8 + k + PD1) * 512);
    }
    const int cb_ = k & 1;
    if (k < 7) {
      #pragma unroll
      for (int n = 0; n < NT; ++n) {           // B k+1 prefetch
        int r = n * 16 + lm;
        int cs = ((k + 1) * 4 + lq) ^ ((lm & 7) << 1);
        bfr2[cb_ ^ 1][n] = *(const v8s*)(xs + r * 256 + cs * 8);
      }
    }
    __builtin_amdgcn_s_setprio(1);
    #pragma unroll
    for (int m = 0; m < MT1; ++m)
      #pragma unroll
      for (int n = 0; n < NT; ++n)
        acc[m][n] = __builtin_amdgcn_mfma_f32_16x16x32_bf16(afb[cur][m], bfr2[cb_][n], acc[m][n], 0, 0, 0);
    __builtin_amdgcn_s_setprio(0);
  }

  // ---- issue phase-2 k=0,1 A-frags: latency hides under epilogue + barrier ----
  v8s afb2[3][2];
  #pragma unroll
  for (int m = 0; m < 2; ++m)
    afb2[0][m] = *(const v8s*)(W2b + (size_t)(m * K2) * 512);
  #pragma unroll
  for (int m = 0; m < 2; ++m)
    afb2[1][m] = *(const v8s*)(W2b + (size_t)(m * K2 + 1) * 512);

  __syncthreads();                           // all xs reads done before overwrite

  const float* b1b = b1 + bin * HID;
  #pragma unroll
  for (int m = 0; m < MT1; ++m) {
    const int f = (w * MT1 + m) * 16 + lq * 4;
    float bb0 = b1b[f], bb1 = b1b[f + 1], bb2 = b1b[f + 2], bb3 = b1b[f + 3];
    #pragma unroll
    for (int n = 0; n < NT; ++n) {
      union { u16 h[4]; uint2 v; } pk;
      f32x4 a = acc[m][n];
      pk.h[0] = f2b(fmaxf(a.x + bb0, 0.f));
      pk.h[1] = f2b(fmaxf(a.y + bb1, 0.f));
      pk.h[2] = f2b(fmaxf(a.z + bb2, 0.f));
      pk.h[3] = f2b(fmaxf(a.w + bb3, 0.f));
      int r = n * 16 + lm;
      int cs = (f >> 3) ^ ((lm & 7) << 1);
      *(uint2*)(uni + (size_t)r * (HID * 2) + (cs << 4) + (f & 7) * 2) = pk.v;
    }
  }
  __syncthreads();

  // ---- phase 2: y^T = W2f * h^T (2-deep A + 1-deep B prefetch) ----
  f32x4 acc2[2][NT];
  #pragma unroll
  for (int m = 0; m < 2; ++m)
    #pragma unroll
    for (int n = 0; n < NT; ++n)
      acc2[m][n] = f32x4{0.f, 0.f, 0.f, 0.f};

  #pragma unroll
  for (int n = 0; n < NT; ++n) {               // B k=0
    int r = n * 16 + lm;
    int cs = lq ^ ((lm & 7) << 1);
    bfr2[0][n] = *(const v8s*)(hs + (size_t)r * HID + cs * 8);
  }
  #pragma unroll
  for (int k = 0; k < K2; ++k) {
    const int cur = k % 3;
    if (k < K2 - 2) {
      const int nx2 = (k + 2) % 3;
      #pragma unroll
      for (int m = 0; m < 2; ++m)
        afb2[nx2][m] = *(const v8s*)(W2b + (size_t)(m * K2 + k + 2) * 512);
    }
    const int cb_ = k & 1;
    if (k < K2 - 1) {
      #pragma unroll
      for (int n = 0; n < NT; ++n) {           // B k+1 prefetch
        int r = n * 16 + lm;
        int cs = ((k + 1) * 4 + lq) ^ ((lm & 7) << 1);
        bfr2[cb_ ^ 1][n] = *(const v8s*)(hs + (size_t)r * HID + cs * 8);
      }
    }
    __builtin_amdgcn_s_setprio(1);
    #pragma unroll
    for (int m = 0; m < 2; ++m)
      #pragma unroll
      for (int n = 0; n < NT; ++n)
        acc2[m][n] = __builtin_amdgcn_mfma_f32_16x16x32_bf16(afb2[cur][m], bfr2[cb_][n], acc2[m][n], 0, 0, 0);
    __builtin_amdgcn_s_setprio(0);
  }

  // ---- epilogue: y -> LDS (XOR-swizzled), FULL-ROW coalesced global write ----
  __syncthreads();                           // all hs reads complete
  const float* b2b = b2 + bin * 128;
  #pragma unroll
  for (int m = 0; m < 2; ++m) {
    const int f = (w * 2 + m) * 16 + lq * 4;
    float bb0 = b2b[f], bb1 = b2b[f + 1], bb2 = b2b[f + 2], bb3 = b2b[f + 3];
    #pragma unroll
    for (int n = 0; n < NT; ++n) {
      union { u16 h[4]; uint2 v; } pk;
      f32x4 a = acc2[m][n];
      pk.h[0] = f2b(a.x + bb0);
      pk.h[1] = f2b(a.y + bb1);
      pk.h[2] = f2b(a.z + bb2);
      pk.h[3] = f2b(a.w + bb3);
      int r = n * 16 + lm;
      int c = (w * 2 + m) * 2 + (lq >> 1);      // 16B chunk within 256B row
      int cs = c ^ ((lm & 7) << 1);
      *(uint2*)(uni + r * 256 + cs * 16 + (lq & 1) * 8) = pk.v;
    }
  }
  __syncthreads();
  // 16 lanes per row: full 256B contiguous lines, no partial-sector RMW
  #pragma unroll
  for (int i = 0; i < MR / 16; ++i) {
    int cg = i * 256 + tid;
    int r = cg >> 4, sub = cg & 15;
    int rg = rid[r];
    if (rg >= 0) {
      uint4 v = *(const uint4*)(uni + r * 256 + ((sub ^ ((r & 7) << 1)) << 4));
      *(uint4*)((char*)dst + (size_t)rg * 256 + sub * 16) = v;
    }
  }
}

// ==================== attention + concat (fp32) ====================
// R12: scores 8-lanes-per-key with shfl_xor reduce; wave-parallel softmax.
__global__ __launch_bounds__(128) void attn_k(
    const u16* __restrict__ stmt, const u16* __restrict__ roots,
    const float* __restrict__ themb, const int* __restrict__ thidx,
    const float* __restrict__ wHe, const float* __restrict__ bHe,
    const float* __restrict__ wHg, const float* __restrict__ bHg,
    const float* __restrict__ wHt, const float* __restrict__ bHt,
    float* __restrict__ out)
{
  const int b = blockIdx.x, t = threadIdx.x;   // 128 threads
  __shared__ float obj_s[128], q_s[128], keys_s[16 * 132], a_s[16];

  const float obj = b2f(stmt[((size_t)b * 9 + 8) * 128 + t]);
  obj_s[t] = obj;
  out[(size_t)b * 512 + t] = obj;              // obj passthrough
  __syncthreads();

  for (int a = 0; a < 3; ++a) {               // 0: gt_ctx, 1: ent_ctx, 2: th_ctx
    int cntk;
    const float *Wt, *bv;
    if (a == 0) {
      cntk = 8; Wt = wHg; bv = bHg;
      for (int j = 0; j < 8; ++j)
        keys_s[j * 132 + t] = b2f(stmt[((size_t)b * 9 + j) * 128 + t]);
    } else if (a == 1) {
      cntk = 16; Wt = wHe; bv = bHe;
      for (int j = 0; j < 16; ++j)
        keys_s[j * 132 + t] = b2f(roots[((size_t)b * 34 + j) * 128 + t]);
    } else {
      cntk = 8; Wt = wHt; bv = bHt;           // TH_MAX = 8
      for (int j = 0; j < 8; ++j) {
        int ti = thidx[b * 8 + j] & 31;        // V_TH = 32
        keys_s[j * 132 + t] = themb[(size_t)ti * 128 + t];
      }
    }
    // q[t] = b[t] + sum_k obj[k] * W[k][t]  (raw [in][out] layout, lane-coalesced)
    float qa = bv[t];
    for (int k = 0; k < 128; ++k) qa += obj_s[k] * Wt[k * 128 + t];
    q_s[t] = (qa == qa) ? qa : 0.f;
    __syncthreads();
    // scores: key j = t>>3, 8 lanes each sum 16 dims, shfl_xor tree reduce
    {
      int j = t >> 3, s = t & 7;
      if (j < cntk) {
        float sc = 0.f;
        #pragma unroll
        for (int k = 0; k < 16; ++k)
          sc += keys_s[j * 132 + s * 16 + k] * q_s[s * 16 + k];
        sc += __shfl_xor(sc, 1);
        sc += __shfl_xor(sc, 2);
        sc += __shfl_xor(sc, 4);
        if (s == 0) a_s[j] = (sc == sc) ? sc : 0.f;
      }
    }
    __syncthreads();
    // wave-parallel softmax over <=16 keys (lanes 0..15 of wave 0)
    if (t < 16) {
      float v = (t < cntk) ? a_s[t] : -3.0e38f;
      float mx = v;
      #pragma unroll
      for (int d = 1; d < 16; d <<= 1) mx = fmaxf(mx, __shfl_xor(mx, d));
      float e = (t < cntk) ? expf(v - mx) : 0.f;
      float sm = e;
      #pragma unroll
      for (int d = 1; d < 16; d <<= 1) sm += __shfl_xor(sm, d);
      if (t < cntk) a_s[t] = e / sm;
    }
    __syncthreads();
    float c = 0.f;
    for (int j = 0; j < cntk; ++j) c += a_s[j] * keys_s[j * 132 + t];
    out[(size_t)b * 512 + 128 * (a + 1) + t] = c;
    __syncthreads();
  }
}

// ==================== launch ====================
extern "C" void kernel_launch(void* const* d_in, const int* in_sizes, int n_in,
                              void* d_out, int out_size, void* d_ws, size_t ws_size,
                              hipStream_t stream)
{
  const int*   leaf_idx = (const int*)d_in[0];
  const int*   nf_ids   = (const int*)d_in[1];
  const int*   lf_ids   = (const int*)d_in[2];
  const int*   th_idx   = (const int*)d_in[3];
  const float* ent_emb  = (const float*)d_in[4];
  const float* th_emb   = (const float*)d_in[5];
  const float* nf_W1 = (const float*)d_in[6];
  const float* nf_b1 = (const float*)d_in[7];
  const float* nf_W2 = (const float*)d_in[8];
  const float* nf_b2 = (const float*)d_in[9];
  const float* lf_W1 = (const float*)d_in[10];
  const float* lf_b1 = (const float*)d_in[11];
  const float* lf_W2 = (const float*)d_in[12];
  const float* lf_b2 = (const float*)d_in[13];
  const float* he_W = (const float*)d_in[14];
  const float* he_b = (const float*)d_in[15];
  const float* hg_W = (const float*)d_in[16];
  const float* hg_b = (const float*)d_in[17];
  const float* ht_W = (const float*)d_in[18];
  const float* ht_b = (const float*)d_in[19];

  // ---- choose chunk size CB (trees per chunk) from ws_size ----
  // footprint ~= 14.5 MB fixed + CB*3320 B (perm 240 + bufA 2048 + bufB 1024 + bh ~4)
  int CB = NTREE;                              // 34816 -> full, no chunking
  while (CB > 544 && 14500000ull + (unsigned long long)CB * 3320ull > (unsigned long long)ws_size)
    CB >>= 1;                                  // 34816,17408,8704,4352,2176,1088,544
  const int nch = NTREE / CB;
  const int NB = (15 * CB + 255) / 256;        // blocks per chunk for the sort passes

  char* ws = (char*)d_ws;
  size_t off = 0;
  auto take = [&](size_t bytes) -> char* {
    char* p = ws + off;
    off = (off + bytes + 255) & ~(size_t)255;
    return p;
  };
  int* cnt      = (int*)take(8192);                       // nch*16 node + 8 leaf
  int* leafperm = (int*)take((size_t)3 * RLEAF * 4);      // 110.6 KB
  int* chperm   = (int*)take((size_t)60 * CB * 4);        // 4 bins x 15CB rows
  int* bh       = (int*)take((size_t)16 * NB * 4);        // block histograms/offsets
  u16* wN1  = (u16*)take((size_t)4 * 256 * 256 * 2);      // 512 KB (frag-packed)
  u16* wN2  = (u16*)take((size_t)4 * 128 * 256 * 2);      // 256 KB
  u16* wL1  = (u16*)take((size_t)3 * 512 * 256 * 2);      // 786 KB
  u16* wL2  = (u16*)take((size_t)3 * 128 * 512 * 2);      // 393 KB
  u16* embB = (u16*)take((size_t)2000 * 128 * 2);         // 512 KB
  u16* bufA  = (u16*)take((size_t)CB * 8 * 128 * 2);      // lvl0 out / lvl2 out
  u16* bufB  = (u16*)take((size_t)CB * 4 * 128 * 2);      // lvl1 out
  u16* roots = (u16*)take((size_t)NTREE * 128 * 2);       // 8.91 MB
  u16* stmt  = (u16*)take((size_t)RLEAF * 128 * 2);       // 2.36 MB

  int* leafcnt = cnt + nch * 16;

  hipMemsetAsync(cnt, 0, (size_t)(nch * 16 + 8) * 4, stream);
  transpose_k<<<4840, 256, 0, stream>>>(nf_W1, nf_W2, lf_W1, lf_W2, ent_emb,
                                        wN1, wN2, wL1, wL2, embB);
  leaf_perm_k<<<36, 256, 0, stream>>>(lf_ids, leafcnt, leafperm);

  for (int c = 0; c < nch; ++c) {
    const int bt0 = c * CB;
    int* ccnt = cnt + c * 16;
    perm_hist_k<<<NB, 256, 0, stream>>>(nf_ids, bh, CB, bt0, NB);
    perm_scan_k<<<1, 1024, 0, stream>>>(bh, ccnt, NB);
    perm_scatter_k<<<NB, 256, 0, stream>>>(nf_ids, bh, chperm, CB, bt0, NB);
    mlp_k<256, 4, 0, 96><<<(8 * CB + 95) / 96 + 4, 256, 0, stream>>>(
        nullptr, leaf_idx, embB, chperm, ccnt, 8 * CB, bt0,
        wN1, nf_b1, wN2, nf_b2, bufA);
    mlp_k<256, 4, 1, 96><<<(4 * CB + 95) / 96 + 4, 256, 0, stream>>>(
        bufA, nullptr, nullptr, chperm + 32 * CB, ccnt + 4, 4 * CB, 0,
        wN1, nf_b1, wN2, nf_b2, bufB);
    mlp_k<256, 4, 1, 64><<<(2 * CB + 63) / 64 + 4, 256, 0, stream>>>(
        bufB, nullptr, nullptr, chperm + 48 * CB, ccnt + 8, 2 * CB, 0,
        wN1, nf_b1, wN2, nf_b2, bufA);
    mlp_k<256, 4, 1, 64><<<(CB + 63) / 64 + 4, 256, 0, stream>>>(
        bufA, nullptr, nullptr, chperm + 56 * CB, ccnt + 12, CB, 0,
        wN1, nf_b1, wN2, nf_b2, roots + (size_t)bt0 * 128);
  }

  mlp_k<512, 3, 2, 32><<<RLEAF / 32 + 3, 256, 0, stream>>>(
      roots, nullptr, nullptr, leafperm, leafcnt, RLEAF, 0,
      wL1, lf_b1, wL2, lf_b2, stmt);

  attn_k<<<1024, 128, 0, stream>>>(stmt, roots, th_emb, th_idx,
                                   he_W, he_b, hg_W, hg_b, ht_W, ht_b,
                                   (float*)d_out);
}

// Round 13
// 291.967 us; speedup vs baseline: 1.1151x; 1.0221x over previous
//
#include <hip/hip_runtime.h>
#include <math.h>

// RecursiveAttentiveEncoder — MoE-sorted MFMA, ws_size-adaptive chunking.
// R6 sort, R7 frag-pack+LDS-stage, R9 A-prefetch, R10 LDS-tiled transpose,
// R12 full-row writes + parallel attn, R13 2-deep A-prefetch + MR=96,
// R14 B-frag dbuf + setprio + merged barrier, R17 re-anchor + MR64 lvl2/3
// (298.4us, lvl0 72.5, MfmaUtil 32%, 5.0M cf, no spill).
// R15 FAILED: additive-rotation swizzle broke the bank map (XOR is the floor).
// R16 FAILED: reg-staged async split spilled (both halves live at peak).
// R18: x staging via __builtin_amdgcn_global_load_lds width=16 (HBM->LDS DMA,
// no VGPR round-trip; frees the 48 staging VGPRs + ds_writes). LDS dest is
// linear (wave-uniform base + lane*16); the XOR swizzle is applied by
// PRE-SWIZZLING the global source chunk (involution, bits1-3 only -> each
// 16-lane group stays inside one 256B segment, coalescing unchanged; LDS
// content bit-identical to R17, all reads untouched).

typedef unsigned short u16;
typedef unsigned int   u32;
typedef unsigned long long u64;
typedef __attribute__((ext_vector_type(8))) short v8s;   // 8 bf16 (4 VGPRs)
typedef __attribute__((ext_vector_type(4))) float f32x4; // MFMA acc

__device__ __forceinline__ float b2f(u16 u) { return __uint_as_float(((u32)u) << 16); }
__device__ __forceinline__ u16 f2b(float f) {
  f = (f == f) ? f : 0.f;                    // NaN squash (hygiene)
  u32 x = __float_as_uint(f);
  u32 r = x + 0x7fffu + ((x >> 16) & 1u);
  return (u16)(r >> 16);
}

__device__ __forceinline__ void g2lds16(const void* g, void* l) {
  __builtin_amdgcn_global_load_lds(
      (const __attribute__((address_space(1))) void*)g,
      (__attribute__((address_space(3))) void*)l, 16, 0, 0);
}

#define NTREE 34816   // B*T_TREES = 1024*34
#define RLEAF 9216    // B*(GT_MAX+1)

// ==================== per-chunk expert sort (node levels) ====================
// 3-pass counting sort. gid in [0,15*CB): [0,8CB)=lvl0, [8CB,12CB)=lvl1,
// [12CB,14CB)=lvl2, [14CB,15CB)=lvl3. CB multiple of 32 -> every level
// boundary is 64-aligned -> each wave is level-uniform (tail lanes id=-1).

// ---- pass A: per-block histogram (LDS atomics only; plain global stores) ----
__global__ __launch_bounds__(256) void perm_hist_k(
    const int* __restrict__ nf, int* __restrict__ bh,
    const int CB, const int bt0, const int nb)
{
  const int gid = blockIdx.x * 256 + threadIdx.x;
  int id = -1, lr = 0, cofs = 12, ioff = 14, shift = 0;
  if (gid < 8 * CB)       { lr = gid;          cofs = 0;  ioff = 0;  shift = 3; }
  else if (gid < 12 * CB) { lr = gid - 8*CB;   cofs = 4;  ioff = 8;  shift = 2; }
  else if (gid < 14 * CB) { lr = gid - 12*CB;  cofs = 8;  ioff = 12; shift = 1; }
  else if (gid < 15 * CB) { lr = gid - 14*CB;  /* lvl3 defaults above */        }
  if (gid < 15 * CB) {
    int bt = bt0 + (lr >> shift);
    int n  = lr & ((1 << shift) - 1);
    id = nf[bt * 15 + ioff + n];
  }
  __shared__ int lcnt[16];
  if (threadIdx.x < 16) lcnt[threadIdx.x] = 0;
  __syncthreads();
  const int lane = threadIdx.x & 63;
  #pragma unroll
  for (int e = 0; e < 4; ++e) {
    u64 m = __ballot(id == e);
    if (m && lane == __builtin_ctzll(m))
      atomicAdd(&lcnt[cofs + e], (int)__popcll(m));
  }
  __syncthreads();
  if (threadIdx.x < 16)
    bh[threadIdx.x * nb + blockIdx.x] = lcnt[threadIdx.x];
}

// ---- pass B: exclusive scan per slot (one wave per slot), totals -> cnt ----
__global__ __launch_bounds__(1024) void perm_scan_k(
    int* __restrict__ bh, int* __restrict__ cnt, const int nb)
{
  const int s = threadIdx.x >> 6;      // slot 0..15
  const int lane = threadIdx.x & 63;
  int carry = 0;
  for (int b0 = 0; b0 < nb; b0 += 64) {
    const int b = b0 + lane;
    int v = (b < nb) ? bh[s * nb + b] : 0;
    int x = v;                          // inclusive wave scan
    #pragma unroll
    for (int d = 1; d < 64; d <<= 1) {
      int y = __shfl_up(x, d);
      if (lane >= d) x += y;
    }
    if (b < nb) bh[s * nb + b] = carry + x - v;   // exclusive, in place
    carry += __shfl(x, 63);
  }
  if (lane == 0) cnt[s] = carry;       // bin totals (no atomics, no memset dep)
}

// ---- pass C: rank + scatter (no global atomics) ----
__global__ __launch_bounds__(256) void perm_scatter_k(
    const int* __restrict__ nf, const int* __restrict__ bh,
    int* __restrict__ perm, const int CB, const int bt0, const int nb)
{
  const int gid = blockIdx.x * 256 + threadIdx.x;
  int id = -1, lr = 0, rows = CB, cofs = 12, pofs = 56 * CB, ioff = 14, shift = 0;
  if (gid < 8 * CB)       { lr = gid;          rows = 8*CB; cofs = 0;  pofs = 0;      ioff = 0;  shift = 3; }
  else if (gid < 12 * CB) { lr = gid - 8*CB;   rows = 4*CB; cofs = 4;  pofs = 32*CB;  ioff = 8;  shift = 2; }
  else if (gid < 14 * CB) { lr = gid - 12*CB;  rows = 2*CB; cofs = 8;  pofs = 48*CB;  ioff = 12; shift = 1; }
  else if (gid < 15 * CB) { lr = gid - 14*CB;  /* lvl3 defaults above */               }
  if (gid < 15 * CB) {
    int bt = bt0 + (lr >> shift);
    int n  = lr & ((1 << shift) - 1);
    id = nf[bt * 15 + ioff + n];
  }
  __shared__ int wc[4][16];
  const int w = threadIdx.x >> 6, lane = threadIdx.x & 63;
  if (lane < 16) wc[w][lane] = 0;
  __syncthreads();
  u64 msave[4];
  #pragma unroll
  for (int e = 0; e < 4; ++e) {
    u64 m = __ballot(id == e);
    msave[e] = m;
    if (m && lane == __builtin_ctzll(m))
      wc[w][cofs + e] = (int)__popcll(m);
  }
  __syncthreads();
  #pragma unroll
  for (int e = 0; e < 4; ++e) {
    if (id == e) {
      const int slot = cofs + e;
      int base = bh[slot * nb + blockIdx.x];        // global rank of block's bin start
      #pragma unroll
      for (int w2 = 0; w2 < 3; ++w2)
        if (w2 < w) base += wc[w2][slot];           // intra-block wave prefix
      perm[pofs + e * rows + base +
           (int)__popcll(msave[e] & ((1ull << lane) - 1ull))] = lr;
    }
  }
}

// ==================== leaf-stage expert sort ====================
// 36 blocks x 3 experts -> ~144 atomics/address: negligible, keep single-pass.
__global__ __launch_bounds__(256) void leaf_perm_k(
    const int* __restrict__ lf, int* __restrict__ cnt, int* __restrict__ perm)
{
  const int gid = blockIdx.x * 256 + threadIdx.x;   // 36*256 = 9216 exact
  const int id = lf[gid];
  const int lane = threadIdx.x & 63;
  for (int e = 0; e < 3; ++e) {
    u64 m = __ballot(id == e);
    if (!m) continue;
    int leader = __builtin_ctzll(m);
    int bp = 0;
    if (lane == leader) bp = atomicAdd(&cnt[e], (int)__popcll(m));
    bp = __shfl(bp, leader);
    if (id == e)
      perm[e * RLEAF + bp + (int)__popcll(m & ((1ull << lane) - 1ull))] = gid;
  }
}

// ==================== weight convert + FRAGMENT-PACK (f32 -> bf16) ====================
// MFMA A-fragment for 16x16x32: lane l holds row=mt*16+(l&15), k=kt*32+(l>>4)*8+j.
// Packed block = 512 u16 = 1KB; wave load = base + lane*16B (coalesced).
// LDS-tiled: one 256-thread block = one 16x16 f32 source tile; coalesced 64B
// row reads; frag-packed write from LDS. (R10)
__global__ __launch_bounds__(256) void transpose_k(
    const float* __restrict__ s0, const float* __restrict__ s1,
    const float* __restrict__ s2, const float* __restrict__ s3,
    const float* __restrict__ s4,
    u16* __restrict__ d0, u16* __restrict__ d1, u16* __restrict__ d2,
    u16* __restrict__ d3, u16* __restrict__ d4)
{
  __shared__ float tile[16][17];
  const int t = threadIdx.x;
  const int idx0 = blockIdx.x * 256;           // block-uniform
  if (idx0 < 983040) {                         // the four frag-packed tensors
    const float* s; u16* d; int tb, estr, O, kt, mt, e;
    int tloc0;
    if (idx0 < 262144)      { s = s0; d = d0; tb = 0;      estr = 65536;  O = 256; }
    else if (idx0 < 393216) { s = s1; d = d1; tb = 262144; estr = 32768;  O = 128; }
    else if (idx0 < 786432) { s = s2; d = d2; tb = 393216; estr = 131072; O = 512; }
    else                    { s = s3; d = d3; tb = 786432; estr = 65536;  O = 128; }
    tloc0 = idx0 - tb;
    const int blk = tloc0 >> 9;                // frag-block id
    const int hb  = (tloc0 >> 8) & 1;          // which half of the frag block
    if (idx0 < 262144)      { kt = blk & 7;  mt = (blk >> 3) & 15; e = blk >> 7; }
    else if (idx0 < 393216) { kt = blk & 7;  mt = (blk >> 3) & 7;  e = blk >> 6; }
    else if (idx0 < 786432) { kt = blk & 7;  mt = (blk >> 3) & 31; e = blk >> 8; }
    else                    { kt = blk & 15; mt = (blk >> 4) & 7;  e = blk >> 7; }
    const int o0 = mt * 16;
    const int k0 = kt * 32 + hb * 16;
    // coalesced tile load: row k0+(t>>4), col o0+(t&15)
    tile[t >> 4][t & 15] = s[(size_t)e * estr + (size_t)(k0 + (t >> 4)) * O + o0 + (t & 15)];
    __syncthreads();
    d[tloc0 + t] = f2b(tile[((t >> 7) << 3) + (t & 7)][(t >> 3) & 15]);
  } else {                                     // ent_emb: already coalesced copy
    int tl = idx0 + t - 983040;
    d4[tl] = f2b(s4[tl]);
  }
}

// ==================== fused expert MLP ====================
// out[r] = relu(x[r] @ W1[bin] + b1[bin]) @ W2[bin] + b2[bin]
// h^T = W1f(A)*x^T(B); y^T = W2f(A)*h^T(B).   rc is a CHUNK-LOCAL row id.
// MODE 0: x = concat(embB[leaf_idx[bt*16+2n]], [..+2n+1]), bt = bt0+(rc>>3)
// MODE 1: x = src + rc*256 elems (pair of prev-level rows, contiguous 512B)
// MODE 2: x = roots rows (b*34+16+2g, +1), b = rc/9, g = rc%9 (contiguous 512B)
// x staged via global_load_lds width=16: linear LDS dest, source chunk
// pre-swizzled by the XOR involution -> LDS content identical to explicit
// swizzled staging. hs and then y reuse the same LDS region.
// A-frags prefetched PD deep (2 for MT1<=4, 1 for leaf); B-frags (ds_read)
// double-buffered one k-step ahead; setprio(1) around MFMA clusters.
template<int HID, int NEXP, int MODE, int MR>
__global__ __launch_bounds__(256, 2) void mlp_k(
    const u16* __restrict__ src, const int* __restrict__ lidx,
    const u16* __restrict__ emb,
    const int* __restrict__ perm, const int* __restrict__ cnt,
    const int rows, const int bt0,
    const u16* __restrict__ W1f, const float* __restrict__ b1,
    const u16* __restrict__ W2f, const float* __restrict__ b2,
    u16* __restrict__ dst)
{
  constexpr int NT  = MR / 16;        // row tiles (B-operand)
  constexpr int MT1 = HID / 64;       // phase-1 m-tiles per wave
  constexpr int K2  = HID / 32;       // phase-2 k-tiles
  constexpr int PD1 = (MT1 <= 4) ? 2 : 1;   // phase-1 A-prefetch depth
  constexpr int NB1 = PD1 + 1;
  constexpr int XB  = MR * 512;       // x staging bytes (MR rows x 512B)
  constexpr int HB  = MR * HID * 2;   // hidden bytes
  constexpr int UB  = XB > HB ? XB : HB;
  __shared__ __align__(16) char uni[UB];       // x (ph1) -> h (ph2) -> y (epi)
  __shared__ int rid[MR], soff[2 * MR];
  u16* const xs = (u16*)uni;
  u16* const hs = (u16*)uni;

  int bin = -1, tile = 0, cb = 0;
  {
    int rem = blockIdx.x;
    #pragma unroll
    for (int e = 0; e < NEXP; ++e) {
      int ce = cnt[e];
      int tt = (ce + MR - 1) / MR;
      if (bin < 0) {
        if (rem < tt) { bin = e; tile = rem; cb = ce; }
        else rem -= tt;
      }
    }
  }
  if (bin < 0) return;
  const int rbase = tile * MR;
  const int tid = threadIdx.x;
  const int w  = tid >> 6;
  const int lane = tid & 63;
  const int lm = lane & 15;
  const int lq = lane >> 4;

  // A-frag base pointers: frag (m,k) at W1b + (m*8+k)*512 / W2b + (m*K2+k)*512
  const u16* const W1b = W1f + ((size_t)(bin * (HID / 16) + w * MT1) << 12) + lane * 8;
  const u16* const W2b = W2f + ((size_t)((bin * 8 + w * 2) * K2) << 9) + lane * 8;

  // ---- issue phase-1 A-frags k=0..PD1-1: latency hides under staging ----
  v8s afb[NB1][MT1];
  #pragma unroll
  for (int d = 0; d < PD1; ++d)
    #pragma unroll
    for (int m = 0; m < MT1; ++m)
      afb[d][m] = *(const v8s*)(W1b + (size_t)(m * 8 + d) * 512);

  // ---- row table + source offsets (merged, ONE sync) ----
  if (tid < MR) {
    int rl = rbase + tid;
    int rlc = rl < cb ? rl : (cb - 1);
    rlc = rlc < 0 ? 0 : rlc;
    int rc = perm[(size_t)bin * rows + rlc];
    rc = rc < 0 ? 0 : (rc >= rows ? rows - 1 : rc);   // defensive
    rid[tid] = (rl < cb) ? rc : -1;
    if (MODE == 0) {
      int bt = bt0 + (rc >> 3), node = rc & 7;
      int ia = lidx[bt * 16 + node * 2];
      int ib = lidx[bt * 16 + node * 2 + 1];
      ia = ia < 0 ? 0 : (ia > 1999 ? 1999 : ia);      // V_ENT=2000, defensive
      ib = ib < 0 ? 0 : (ib > 1999 ? 1999 : ib);
      soff[2 * tid]     = ia * 256;
      soff[2 * tid + 1] = ib * 256;
    } else {
      int base;
      if (MODE == 1) base = rc * 512;
      else { int bq = rc / 9, g = rc - bq * 9; base = (bq * 34 + 16 + 2 * g) * 256; }
      soff[2 * tid]     = base;
      soff[2 * tid + 1] = base + 256;
    }
  }
  __syncthreads();

  // ---- stage x: global_load_lds, linear LDS dest + pre-swizzled source ----
  // Linear dest chunk d (row r=d>>5, c32d=d&31) receives source chunk
  // cS = c32d ^ ((r&7)<<1) (involution) -> LDS[slot] holds the same bytes as
  // explicit swizzled staging. XOR touches bits1-3 only -> each 16-lane group
  // stays within one 256B source segment (coalesced).
  const char* const sb = (MODE == 0) ? (const char*)emb : (const char*)src;
  #pragma unroll
  for (int i = 0; i < MR / 8; ++i) {
    int d = i * 256 + tid;
    int r = d >> 5, c32d = d & 31;
    int cS = c32d ^ ((r & 7) << 1);
    const char* ga = sb + (size_t)(u32)soff[2 * r + (cS >> 4)] + (cS & 15) * 16;
    char* la = uni + ((size_t)(i * 256 + (tid & 192)) << 4);  // wave-uniform base
    g2lds16(ga, la);
  }
  __syncthreads();

  int rdn[NT];
  #pragma unroll
  for (int n = 0; n < NT; ++n) rdn[n] = rid[n * 16 + lm];

  // ---- phase 1: h^T = W1f * x^T, +b1, relu -> hs (same LDS) ----
  f32x4 acc[MT1][NT];
  #pragma unroll
  for (int m = 0; m < MT1; ++m)
    #pragma unroll
    for (int n = 0; n < NT; ++n)
      acc[m][n] = f32x4{0.f, 0.f, 0.f, 0.f};

  v8s bfr2[2][NT];
  #pragma unroll
  for (int n = 0; n < NT; ++n) {               // B k=0
    int r = n * 16 + lm;
    int cs = lq ^ ((lm & 7) << 1);
    bfr2[0][n] = *(const v8s*)(xs + r * 256 + cs * 8);
  }
  #pragma unroll
  for (int k = 0; k < 8; ++k) {                // K = 256
    const int cur = k % NB1;
    if (k + PD1 < 8) {
      const int nx = (k + PD1) % NB1;
      #pragma unroll
      for (int m = 0; m < MT1; ++m)
        afb[nx][m] = *(const v8s*)(W1b + (size_t)(m * 8 + k + PD1) * 512);
    }
    const int cb_ = k & 1;
    if (k < 7) {
      #pragma unroll
      for (int n = 0; n < NT; ++n) {           // B k+1 prefetch
        int r = n * 16 + lm;
        int cs = ((k + 1) * 4 + lq) ^ ((lm & 7) << 1);
        bfr2[cb_ ^ 1][n] = *(const v8s*)(xs + r * 256 + cs * 8);
      }
    }
    __builtin_amdgcn_s_setprio(1);
    #pragma unroll
    for (int m = 0; m < MT1; ++m)
      #pragma unroll
      for (int n = 0; n < NT; ++n)
        acc[m][n] = __builtin_amdgcn_mfma_f32_16x16x32_bf16(afb[cur][m], bfr2[cb_][n], acc[m][n], 0, 0, 0);
    __builtin_amdgcn_s_setprio(0);
  }

  // ---- issue phase-2 k=0,1 A-frags: latency hides under epilogue + barrier ----
  v8s afb2[3][2];
  #pragma unroll
  for (int m = 0; m < 2; ++m)
    afb2[0][m] = *(const v8s*)(W2b + (size_t)(m * K2) * 512);
  #pragma unroll
  for (int m = 0; m < 2; ++m)
    afb2[1][m] = *(const v8s*)(W2b + (size_t)(m * K2 + 1) * 512);

  __syncthreads();                           // all xs reads done before overwrite

  const float* b1b = b1 + bin * HID;
  #pragma unroll
  for (int m = 0; m < MT1; ++m) {
    const int f = (w * MT1 + m) * 16 + lq * 4;
    float bb0 = b1b[f], bb1 = b1b[f + 1], bb2 = b1b[f + 2], bb3 = b1b[f + 3];
    #pragma unroll
    for (int n = 0; n < NT; ++n) {
      union { u16 h[4]; uint2 v; } pk;
      f32x4 a = acc[m][n];
      pk.h[0] = f2b(fmaxf(a.x + bb0, 0.f));
      pk.h[1] = f2b(fmaxf(a.y + bb1, 0.f));
      pk.h[2] = f2b(fmaxf(a.z + bb2, 0.f));
      pk.h[3] = f2b(fmaxf(a.w + bb3, 0.f));
      int r = n * 16 + lm;
      int cs = (f >> 3) ^ ((lm & 7) << 1);
      *(uint2*)(uni + (size_t)r * (HID * 2) + (cs << 4) + (f & 7) * 2) = pk.v;
    }
  }
  __syncthreads();

  // ---- phase 2: y^T = W2f * h^T (2-deep A + 1-deep B prefetch) ----
  f32x4 acc2[2][NT];
  #pragma unroll
  for (int m = 0; m < 2; ++m)
    #pragma unroll
    for (int n = 0; n < NT; ++n)
      acc2[m][n] = f32x4{0.f, 0.f, 0.f, 0.f};

  #pragma unroll
  for (int n = 0; n < NT; ++n) {               // B k=0
    int r = n * 16 + lm;
    int cs = lq ^ ((lm & 7) << 1);
    bfr2[0][n] = *(const v8s*)(hs + (size_t)r * HID + cs * 8);
  }
  #pragma unroll
  for (int k = 0; k < K2; ++k) {
    const int cur = k % 3;
    if (k < K2 - 2) {
      const int nx2 = (k + 2) % 3;
      #pragma unroll
      for (int m = 0; m < 2; ++m)
        afb2[nx2][m] = *(const v8s*)(W2b + (size_t)(m * K2 + k + 2) * 512);
    }
    const int cb_ = k & 1;
    if (k < K2 - 1) {
      #pragma unroll
      for (int n = 0; n < NT; ++n) {           // B k+1 prefetch
        int r = n * 16 + lm;
        int cs = ((k + 1) * 4 + lq) ^ ((lm & 7) << 1);
        bfr2[cb_ ^ 1][n] = *(const v8s*)(hs + (size_t)r * HID + cs * 8);
      }
    }
    __builtin_amdgcn_s_setprio(1);
    #pragma unroll
    for (int m = 0; m < 2; ++m)
      #pragma unroll
      for (int n = 0; n < NT; ++n)
        acc2[m][n] = __builtin_amdgcn_mfma_f32_16x16x32_bf16(afb2[cur][m], bfr2[cb_][n], acc2[m][n], 0, 0, 0);
    __builtin_amdgcn_s_setprio(0);
  }

  // ---- epilogue: y -> LDS (XOR-swizzled), FULL-ROW coalesced global write ----
  __syncthreads();                           // all hs reads complete
  const float* b2b = b2 + bin * 128;
  #pragma unroll
  for (int m = 0; m < 2; ++m) {
    const int f = (w * 2 + m) * 16 + lq * 4;
    float bb0 = b2b[f], bb1 = b2b[f + 1], bb2 = b2b[f + 2], bb3 = b2b[f + 3];
    #pragma unroll
    for (int n = 0; n < NT; ++n) {
      union { u16 h[4]; uint2 v; } pk;
      f32x4 a = acc2[m][n];
      pk.h[0] = f2b(a.x + bb0);
      pk.h[1] = f2b(a.y + bb1);
      pk.h[2] = f2b(a.z + bb2);
      pk.h[3] = f2b(a.w + bb3);
      int r = n * 16 + lm;
      int c = (w * 2 + m) * 2 + (lq >> 1);      // 16B chunk within 256B row
      int cs = c ^ ((lm & 7) << 1);
      *(uint2*)(uni + r * 256 + cs * 16 + (lq & 1) * 8) = pk.v;
    }
  }
  __syncthreads();
  // 16 lanes per row: full 256B contiguous lines, no partial-sector RMW
  #pragma unroll
  for (int i = 0; i < MR / 16; ++i) {
    int cg = i * 256 + tid;
    int r = cg >> 4, sub = cg & 15;
    int rg = rid[r];
    if (rg >= 0) {
      uint4 v = *(const uint4*)(uni + r * 256 + ((sub ^ ((r & 7) << 1)) << 4));
      *(uint4*)((char*)dst + (size_t)rg * 256 + sub * 16) = v;
    }
  }
}

// ==================== attention + concat (fp32) ====================
// R12: scores 8-lanes-per-key with shfl_xor reduce; wave-parallel softmax.
__global__ __launch_bounds__(128) void attn_k(
    const u16* __restrict__ stmt, const u16* __restrict__ roots,
    const float* __restrict__ themb, const int* __restrict__ thidx,
    const float* __restrict__ wHe, const float* __restrict__ bHe,
    const float* __restrict__ wHg, const float* __restrict__ bHg,
    const float* __restrict__ wHt, const float* __restrict__ bHt,
    float* __restrict__ out)
{
  const int b = blockIdx.x, t = threadIdx.x;   // 128 threads
  __shared__ float obj_s[128], q_s[128], keys_s[16 * 132], a_s[16];

  const float obj = b2f(stmt[((size_t)b * 9 + 8) * 128 + t]);
  obj_s[t] = obj;
  out[(size_t)b * 512 + t] = obj;              // obj passthrough
  __syncthreads();

  for (int a = 0; a < 3; ++a) {               // 0: gt_ctx, 1: ent_ctx, 2: th_ctx
    int cntk;
    const float *Wt, *bv;
    if (a == 0) {
      cntk = 8; Wt = wHg; bv = bHg;
      for (int j = 0; j < 8; ++j)
        keys_s[j * 132 + t] = b2f(stmt[((size_t)b * 9 + j) * 128 + t]);
    } else if (a == 1) {
      cntk = 16; Wt = wHe; bv = bHe;
      for (int j = 0; j < 16; ++j)
        keys_s[j * 132 + t] = b2f(roots[((size_t)b * 34 + j) * 128 + t]);
    } else {
      cntk = 8; Wt = wHt; bv = bHt;           // TH_MAX = 8
      for (int j = 0; j < 8; ++j) {
        int ti = thidx[b * 8 + j] & 31;        // V_TH = 32
        keys_s[j * 132 + t] = themb[(size_t)ti * 128 + t];
      }
    }
    // q[t] = b[t] + sum_k obj[k] * W[k][t]  (raw [in][out] layout, lane-coalesced)
    float qa = bv[t];
    for (int k = 0; k < 128; ++k) qa += obj_s[k] * Wt[k * 128 + t];
    q_s[t] = (qa == qa) ? qa : 0.f;
    __syncthreads();
    // scores: key j = t>>3, 8 lanes each sum 16 dims, shfl_xor tree reduce
    {
      int j = t >> 3, s = t & 7;
      if (j < cntk) {
        float sc = 0.f;
        #pragma unroll
        for (int k = 0; k < 16; ++k)
          sc += keys_s[j * 132 + s * 16 + k] * q_s[s * 16 + k];
        sc += __shfl_xor(sc, 1);
        sc += __shfl_xor(sc, 2);
        sc += __shfl_xor(sc, 4);
        if (s == 0) a_s[j] = (sc == sc) ? sc : 0.f;
      }
    }
    __syncthreads();
    // wave-parallel softmax over <=16 keys (lanes 0..15 of wave 0)
    if (t < 16) {
      float v = (t < cntk) ? a_s[t] : -3.0e38f;
      float mx = v;
      #pragma unroll
      for (int d = 1; d < 16; d <<= 1) mx = fmaxf(mx, __shfl_xor(mx, d));
      float e = (t < cntk) ? expf(v - mx) : 0.f;
      float sm = e;
      #pragma unroll
      for (int d = 1; d < 16; d <<= 1) sm += __shfl_xor(sm, d);
      if (t < cntk) a_s[t] = e / sm;
    }
    __syncthreads();
    float c = 0.f;
    for (int j = 0; j < cntk; ++j) c += a_s[j] * keys_s[j * 132 + t];
    out[(size_t)b * 512 + 128 * (a + 1) + t] = c;
    __syncthreads();
  }
}

// ==================== launch ====================
extern "C" void kernel_launch(void* const* d_in, const int* in_sizes, int n_in,
                              void* d_out, int out_size, void* d_ws, size_t ws_size,
                              hipStream_t stream)
{
  const int*   leaf_idx = (const int*)d_in[0];
  const int*   nf_ids   = (const int*)d_in[1];
  const int*   lf_ids   = (const int*)d_in[2];
  const int*   th_idx   = (const int*)d_in[3];
  const float* ent_emb  = (const float*)d_in[4];
  const float* th_emb   = (const float*)d_in[5];
  const float* nf_W1 = (const float*)d_in[6];
  const float* nf_b1 = (const float*)d_in[7];
  const float* nf_W2 = (const float*)d_in[8];
  const float* nf_b2 = (const float*)d_in[9];
  const float* lf_W1 = (const float*)d_in[10];
  const float* lf_b1 = (const float*)d_in[11];
  const float* lf_W2 = (const float*)d_in[12];
  const float* lf_b2 = (const float*)d_in[13];
  const float* he_W = (const float*)d_in[14];
  const float* he_b = (const float*)d_in[15];
  const float* hg_W = (const float*)d_in[16];
  const float* hg_b = (const float*)d_in[17];
  const float* ht_W = (const float*)d_in[18];
  const float* ht_b = (const float*)d_in[19];

  // ---- choose chunk size CB (trees per chunk) from ws_size ----
  // footprint ~= 14.5 MB fixed + CB*3320 B (perm 240 + bufA 2048 + bufB 1024 + bh ~4)
  int CB = NTREE;                              // 34816 -> full, no chunking
  while (CB > 544 && 14500000ull + (unsigned long long)CB * 3320ull > (unsigned long long)ws_size)
    CB >>= 1;                                  // 34816,17408,8704,4352,2176,1088,544
  const int nch = NTREE / CB;
  const int NB = (15 * CB + 255) / 256;        // blocks per chunk for the sort passes

  char* ws = (char*)d_ws;
  size_t off = 0;
  auto take = [&](size_t bytes) -> char* {
    char* p = ws + off;
    off = (off + bytes + 255) & ~(size_t)255;
    return p;
  };
  int* cnt      = (int*)take(8192);                       // nch*16 node + 8 leaf
  int* leafperm = (int*)take((size_t)3 * RLEAF * 4);      // 110.6 KB
  int* chperm   = (int*)take((size_t)60 * CB * 4);        // 4 bins x 15CB rows
  int* bh       = (int*)take((size_t)16 * NB * 4);        // block histograms/offsets
  u16* wN1  = (u16*)take((size_t)4 * 256 * 256 * 2);      // 512 KB (frag-packed)
  u16* wN2  = (u16*)take((size_t)4 * 128 * 256 * 2);      // 256 KB
  u16* wL1  = (u16*)take((size_t)3 * 512 * 256 * 2);      // 786 KB
  u16* wL2  = (u16*)take((size_t)3 * 128 * 512 * 2);      // 393 KB
  u16* embB = (u16*)take((size_t)2000 * 128 * 2);         // 512 KB
  u16* bufA  = (u16*)take((size_t)CB * 8 * 128 * 2);      // lvl0 out / lvl2 out
  u16* bufB  = (u16*)take((size_t)CB * 4 * 128 * 2);      // lvl1 out
  u16* roots = (u16*)take((size_t)NTREE * 128 * 2);       // 8.91 MB
  u16* stmt  = (u16*)take((size_t)RLEAF * 128 * 2);       // 2.36 MB

  int* leafcnt = cnt + nch * 16;

  hipMemsetAsync(cnt, 0, (size_t)(nch * 16 + 8) * 4, stream);
  transpose_k<<<4840, 256, 0, stream>>>(nf_W1, nf_W2, lf_W1, lf_W2, ent_emb,
                                        wN1, wN2, wL1, wL2, embB);
  leaf_perm_k<<<36, 256, 0, stream>>>(lf_ids, leafcnt, leafperm);

  for (int c = 0; c < nch; ++c) {
    const int bt0 = c * CB;
    int* ccnt = cnt + c * 16;
    perm_hist_k<<<NB, 256, 0, stream>>>(nf_ids, bh, CB, bt0, NB);
    perm_scan_k<<<1, 1024, 0, stream>>>(bh, ccnt, NB);
    perm_scatter_k<<<NB, 256, 0, stream>>>(nf_ids, bh, chperm, CB, bt0, NB);
    mlp_k<256, 4, 0, 96><<<(8 * CB + 95) / 96 + 4, 256, 0, stream>>>(
        nullptr, leaf_idx, embB, chperm, ccnt, 8 * CB, bt0,
        wN1, nf_b1, wN2, nf_b2, bufA);
    mlp_k<256, 4, 1, 96><<<(4 * CB + 95) / 96 + 4, 256, 0, stream>>>(
        bufA, nullptr, nullptr, chperm + 32 * CB, ccnt + 4, 4 * CB, 0,
        wN1, nf_b1, wN2, nf_b2, bufB);
    mlp_k<256, 4, 1, 64><<<(2 * CB + 63) / 64 + 4, 256, 0, stream>>>(
        bufB, nullptr, nullptr, chperm + 48 * CB, ccnt + 8, 2 * CB, 0,
        wN1, nf_b1, wN2, nf_b2, bufA);
    mlp_k<256, 4, 1, 64><<<(CB + 63) / 64 + 4, 256, 0, stream>>>(
        bufA, nullptr, nullptr, chperm + 56 * CB, ccnt + 12, CB, 0,
        wN1, nf_b1, wN2, nf_b2, roots + (size_t)bt0 * 128);
  }

  mlp_k<512, 3, 2, 32><<<RLEAF / 32 + 3, 256, 0, stream>>>(
      roots, nullptr, nullptr, leafperm, leafcnt, RLEAF, 0,
      wL1, lf_b1, wL2, lf_b2, stmt);

  attn_k<<<1024, 128, 0, stream>>>(stmt, roots, th_emb, th_idx,
                                   he_W, he_b, hg_W, hg_b, ht_W, ht_b,
                                   (float*)d_out);
}